// Round 3
// baseline (704.091 us; speedup 1.0000x reference)
//
#include <hip/hip_runtime.h>
#include <math.h>

// ---------------- CSR build ----------------

__global__ __launch_bounds__(256) void k_count(const int* __restrict__ dst,
                                               int* __restrict__ cnt, int e) {
    int i = blockIdx.x * 256 + threadIdx.x;
    if (i < e) atomicAdd(&cnt[dst[i]], 1);
}

__global__ __launch_bounds__(256) void k_scan_local(const int* __restrict__ cnt,
                                                    int* __restrict__ row_start,
                                                    int* __restrict__ partials, int n) {
    __shared__ int sdata[256];
    int tid = threadIdx.x;
    int base = blockIdx.x * 1024 + tid * 4;
    int v0 = (base + 0 < n) ? cnt[base + 0] : 0;
    int v1 = (base + 1 < n) ? cnt[base + 1] : 0;
    int v2 = (base + 2 < n) ? cnt[base + 2] : 0;
    int v3 = (base + 3 < n) ? cnt[base + 3] : 0;
    int s = v0 + v1 + v2 + v3;
    sdata[tid] = s;
    __syncthreads();
    for (int off = 1; off < 256; off <<= 1) {
        int y = (tid >= off) ? sdata[tid - off] : 0;
        __syncthreads();
        sdata[tid] += y;
        __syncthreads();
    }
    int run = sdata[tid] - s;
    if (base + 0 < n) row_start[base + 0] = run;
    run += v0;
    if (base + 1 < n) row_start[base + 1] = run;
    run += v1;
    if (base + 2 < n) row_start[base + 2] = run;
    run += v2;
    if (base + 3 < n) row_start[base + 3] = run;
    if (tid == 255) partials[blockIdx.x] = sdata[255];
}

__global__ __launch_bounds__(256) void k_scan_partials(int* partials, int nb) {
    __shared__ int sdata[256];
    int tid = threadIdx.x;
    int v = (tid < nb) ? partials[tid] : 0;
    sdata[tid] = v;
    __syncthreads();
    for (int off = 1; off < 256; off <<= 1) {
        int y = (tid >= off) ? sdata[tid - off] : 0;
        __syncthreads();
        sdata[tid] += y;
        __syncthreads();
    }
    if (tid < nb) partials[tid] = sdata[tid] - v;
}

__global__ __launch_bounds__(256) void k_scan_add(int* __restrict__ row_start,
                                                  const int* __restrict__ partials,
                                                  int n, int total) {
    int i = blockIdx.x * 256 + threadIdx.x;
    if (i < n) row_start[i] += partials[i >> 10];
    if (i == 0) row_start[n] = total;
}

__global__ __launch_bounds__(256) void k_scatter(const int* __restrict__ src,
                                                 const int* __restrict__ dst,
                                                 const int* __restrict__ row_start,
                                                 int* __restrict__ fill,
                                                 int* __restrict__ csr_src, int e) {
    int i = blockIdx.x * 256 + threadIdx.x;
    if (i < e) {
        int d = dst[i];
        int pos = row_start[d] + atomicAdd(&fill[d], 1);
        csr_src[pos] = src[i];
    }
}

// ---------------- Layer 1 GEMM: [N,128] @ [128,128] + fused el/er ----------------

__global__ __launch_bounds__(256) void k_gemm1(const float* __restrict__ X,
                                               const float* __restrict__ W,
                                               const float* __restrict__ attn_l,
                                               const float* __restrict__ attn_r,
                                               float* __restrict__ feat,
                                               float* __restrict__ el,
                                               float* __restrict__ er, int n) {
    __shared__ float sW[128 * 128];
    __shared__ float sX[64 * 132];
    int t = threadIdx.x;
    {
        const float4* Wv = (const float4*)W;
        float4* sWv = (float4*)sW;
#pragma unroll
        for (int i = 0; i < 16; ++i) sWv[t + i * 256] = Wv[t + i * 256];
    }
    int node0 = blockIdx.x * 64;
    {
        const float4* Xv = (const float4*)X;
        for (int i = t; i < 64 * 32; i += 256) {
            int r = i >> 5, q = i & 31;
            int node = node0 + r;
            float4 val = make_float4(0.f, 0.f, 0.f, 0.f);
            if (node < n) val = Xv[(size_t)node * 32 + q];
            *(float4*)(sX + r * 132 + q * 4) = val;
        }
    }
    __syncthreads();
    int tr = t >> 4, tc = t & 15;
    float acc[4][8] = {};
    for (int k = 0; k < 128; ++k) {
        float4 w0 = *(const float4*)(sW + k * 128 + tc * 8);
        float4 w1 = *(const float4*)(sW + k * 128 + tc * 8 + 4);
#pragma unroll
        for (int i = 0; i < 4; ++i) {
            float xk = sX[(tr + 16 * i) * 132 + k];
            acc[i][0] += xk * w0.x; acc[i][1] += xk * w0.y;
            acc[i][2] += xk * w0.z; acc[i][3] += xk * w0.w;
            acc[i][4] += xk * w1.x; acc[i][5] += xk * w1.y;
            acc[i][6] += xk * w1.z; acc[i][7] += xk * w1.w;
        }
    }
    int h = tc >> 2;
    int dbase = (tc & 3) * 8;
    float al[8], ar[8];
#pragma unroll
    for (int j = 0; j < 8; ++j) {
        al[j] = attn_l[h * 32 + dbase + j];
        ar[j] = attn_r[h * 32 + dbase + j];
    }
#pragma unroll
    for (int i = 0; i < 4; ++i) {
        int node = node0 + tr + 16 * i;
        float pl = 0.f, pr = 0.f;
#pragma unroll
        for (int j = 0; j < 8; ++j) { pl += acc[i][j] * al[j]; pr += acc[i][j] * ar[j]; }
        pl += __shfl_xor(pl, 1); pl += __shfl_xor(pl, 2);
        pr += __shfl_xor(pr, 1); pr += __shfl_xor(pr, 2);
        if (node < n) {
            float4 f0 = make_float4(acc[i][0], acc[i][1], acc[i][2], acc[i][3]);
            float4 f1 = make_float4(acc[i][4], acc[i][5], acc[i][6], acc[i][7]);
            *(float4*)(feat + (size_t)node * 128 + tc * 8) = f0;
            *(float4*)(feat + (size_t)node * 128 + tc * 8 + 4) = f1;
            if ((tc & 3) == 0) { el[node * 4 + h] = pl; er[node * 4 + h] = pr; }
        }
    }
}

// ---------------- Layer 2 GEMM: [N,128] @ [128,64] + fused el/er (H=1) ----------------

__global__ __launch_bounds__(256) void k_gemm2(const float* __restrict__ X,
                                               const float* __restrict__ W,
                                               const float* __restrict__ attn_l,
                                               const float* __restrict__ attn_r,
                                               float* __restrict__ feat,
                                               float* __restrict__ el,
                                               float* __restrict__ er, int n) {
    __shared__ float sW[128 * 64];
    __shared__ float sX[64 * 132];
    int t = threadIdx.x;
    {
        const float4* Wv = (const float4*)W;
        float4* sWv = (float4*)sW;
#pragma unroll
        for (int i = 0; i < 8; ++i) sWv[t + i * 256] = Wv[t + i * 256];
    }
    int node0 = blockIdx.x * 64;
    {
        const float4* Xv = (const float4*)X;
        for (int i = t; i < 64 * 32; i += 256) {
            int r = i >> 5, q = i & 31;
            int node = node0 + r;
            float4 val = make_float4(0.f, 0.f, 0.f, 0.f);
            if (node < n) val = Xv[(size_t)node * 32 + q];
            *(float4*)(sX + r * 132 + q * 4) = val;
        }
    }
    __syncthreads();
    int tr = t >> 3, tc = t & 7;
    float acc[2][8] = {};
    for (int k = 0; k < 128; ++k) {
        float4 w0 = *(const float4*)(sW + k * 64 + tc * 8);
        float4 w1 = *(const float4*)(sW + k * 64 + tc * 8 + 4);
#pragma unroll
        for (int i = 0; i < 2; ++i) {
            float xk = sX[(tr + 32 * i) * 132 + k];
            acc[i][0] += xk * w0.x; acc[i][1] += xk * w0.y;
            acc[i][2] += xk * w0.z; acc[i][3] += xk * w0.w;
            acc[i][4] += xk * w1.x; acc[i][5] += xk * w1.y;
            acc[i][6] += xk * w1.z; acc[i][7] += xk * w1.w;
        }
    }
    float al[8], ar[8];
#pragma unroll
    for (int j = 0; j < 8; ++j) { al[j] = attn_l[tc * 8 + j]; ar[j] = attn_r[tc * 8 + j]; }
#pragma unroll
    for (int i = 0; i < 2; ++i) {
        int node = node0 + tr + 32 * i;
        float pl = 0.f, pr = 0.f;
#pragma unroll
        for (int j = 0; j < 8; ++j) { pl += acc[i][j] * al[j]; pr += acc[i][j] * ar[j]; }
        pl += __shfl_xor(pl, 1); pl += __shfl_xor(pl, 2); pl += __shfl_xor(pl, 4);
        pr += __shfl_xor(pr, 1); pr += __shfl_xor(pr, 2); pr += __shfl_xor(pr, 4);
        if (node < n) {
            float4 f0 = make_float4(acc[i][0], acc[i][1], acc[i][2], acc[i][3]);
            float4 f1 = make_float4(acc[i][4], acc[i][5], acc[i][6], acc[i][7]);
            *(float4*)(feat + (size_t)node * 64 + tc * 8) = f0;
            *(float4*)(feat + (size_t)node * 64 + tc * 8 + 4) = f1;
            if (tc == 0) { el[node] = pl; er[node] = pr; }
        }
    }
}

// ---------------- Attention weights, layer 1 (H=4) ----------------

__global__ __launch_bounds__(256) void k_attn_w1(const int* __restrict__ row_start,
                                                 const int* __restrict__ csr_src,
                                                 const float* __restrict__ el,
                                                 const float* __restrict__ er,
                                                 float* __restrict__ alpha,
                                                 float* __restrict__ rden, int n) {
    int wid = (blockIdx.x * blockDim.x + threadIdx.x) >> 6;
    int lane = threadIdx.x & 63;
    if (wid >= n) return;
    int start = row_start[wid], end = row_start[wid + 1];
    float4 er4 = *(const float4*)(er + wid * 4);
    float m0 = -INFINITY, m1 = -INFINITY, m2 = -INFINITY, m3 = -INFINITY;
    for (int slot = start + lane; slot < end; slot += 64) {
        int s = csr_src[slot];
        float4 e4 = *(const float4*)(el + s * 4);
        float e0 = e4.x + er4.x, e1 = e4.y + er4.y, e2 = e4.z + er4.z, e3 = e4.w + er4.w;
        e0 = (e0 > 0.f) ? e0 : 0.2f * e0;
        e1 = (e1 > 0.f) ? e1 : 0.2f * e1;
        e2 = (e2 > 0.f) ? e2 : 0.2f * e2;
        e3 = (e3 > 0.f) ? e3 : 0.2f * e3;
        m0 = fmaxf(m0, e0); m1 = fmaxf(m1, e1); m2 = fmaxf(m2, e2); m3 = fmaxf(m3, e3);
    }
#pragma unroll
    for (int off = 1; off < 64; off <<= 1) {
        m0 = fmaxf(m0, __shfl_xor(m0, off));
        m1 = fmaxf(m1, __shfl_xor(m1, off));
        m2 = fmaxf(m2, __shfl_xor(m2, off));
        m3 = fmaxf(m3, __shfl_xor(m3, off));
    }
    float d0 = 0.f, d1 = 0.f, d2 = 0.f, d3 = 0.f;
    for (int slot = start + lane; slot < end; slot += 64) {
        int s = csr_src[slot];
        float4 e4 = *(const float4*)(el + s * 4);
        float e0 = e4.x + er4.x, e1 = e4.y + er4.y, e2 = e4.z + er4.z, e3 = e4.w + er4.w;
        e0 = (e0 > 0.f) ? e0 : 0.2f * e0;
        e1 = (e1 > 0.f) ? e1 : 0.2f * e1;
        e2 = (e2 > 0.f) ? e2 : 0.2f * e2;
        e3 = (e3 > 0.f) ? e3 : 0.2f * e3;
        float w0 = __expf(e0 - m0), w1 = __expf(e1 - m1);
        float w2 = __expf(e2 - m2), w3 = __expf(e3 - m3);
        d0 += w0; d1 += w1; d2 += w2; d3 += w3;
        *(float4*)(alpha + (size_t)slot * 4) = make_float4(w0, w1, w2, w3);
    }
#pragma unroll
    for (int off = 1; off < 64; off <<= 1) {
        d0 += __shfl_xor(d0, off);
        d1 += __shfl_xor(d1, off);
        d2 += __shfl_xor(d2, off);
        d3 += __shfl_xor(d3, off);
    }
    if (lane == 0) {
        float4 rd;
        rd.x = (d0 > 0.f) ? 1.f / d0 : 0.f;
        rd.y = (d1 > 0.f) ? 1.f / d1 : 0.f;
        rd.z = (d2 > 0.f) ? 1.f / d2 : 0.f;
        rd.w = (d3 > 0.f) ? 1.f / d3 : 0.f;
        *(float4*)(rden + wid * 4) = rd;
    }
}

// ---------------- Attention weights, layer 2 (H=1) ----------------

__global__ __launch_bounds__(256) void k_attn_w2(const int* __restrict__ row_start,
                                                 const int* __restrict__ csr_src,
                                                 const float* __restrict__ el,
                                                 const float* __restrict__ er,
                                                 float* __restrict__ alpha,
                                                 float* __restrict__ rden, int n) {
    int wid = (blockIdx.x * blockDim.x + threadIdx.x) >> 6;
    int lane = threadIdx.x & 63;
    if (wid >= n) return;
    int start = row_start[wid], end = row_start[wid + 1];
    float erv = er[wid];
    float m = -INFINITY;
    for (int slot = start + lane; slot < end; slot += 64) {
        int s = csr_src[slot];
        float e = el[s] + erv;
        e = (e > 0.f) ? e : 0.2f * e;
        m = fmaxf(m, e);
    }
#pragma unroll
    for (int off = 1; off < 64; off <<= 1) m = fmaxf(m, __shfl_xor(m, off));
    float d = 0.f;
    for (int slot = start + lane; slot < end; slot += 64) {
        int s = csr_src[slot];
        float e = el[s] + erv;
        e = (e > 0.f) ? e : 0.2f * e;
        float w = __expf(e - m);
        d += w;
        alpha[slot] = w;
    }
#pragma unroll
    for (int off = 1; off < 64; off <<= 1) d += __shfl_xor(d, off);
    if (lane == 0) rden[wid] = (d > 0.f) ? 1.f / d : 0.f;
}

// ---------------- Gather-accumulate, layer 1 ----------------
// wave per node; lane l owns dims {2l, 2l+1} (head = l>>4). Fused 1/denom + bias + ELU.

__global__ __launch_bounds__(256) void k_gather1(const int* __restrict__ row_start,
                                                 const int* __restrict__ csr_src,
                                                 const float* __restrict__ feat,
                                                 const float* __restrict__ alpha,
                                                 const float* __restrict__ rden,
                                                 const float* __restrict__ bias,
                                                 float* __restrict__ xout, int n) {
    int wid = (blockIdx.x * blockDim.x + threadIdx.x) >> 6;
    int lane = threadIdx.x & 63;
    if (wid >= n) return;
    int h = lane >> 4;
    int start = row_start[wid], end = row_start[wid + 1];
    float ax = 0.f, ay = 0.f;
    for (int slot = start; slot < end; ++slot) {
        int s = __builtin_amdgcn_readfirstlane(csr_src[slot]);
        float w = alpha[(size_t)slot * 4 + h];
        float2 f = *(const float2*)(feat + (size_t)s * 128 + 2 * lane);
        ax += w * f.x;
        ay += w * f.y;
    }
    float rd = rden[wid * 4 + h];
    float2 b = *(const float2*)(bias + 2 * lane);
    float ox = ax * rd + b.x;
    float oy = ay * rd + b.y;
    ox = (ox > 0.f) ? ox : (__expf(ox) - 1.f);
    oy = (oy > 0.f) ? oy : (__expf(oy) - 1.f);
    *(float2*)(xout + (size_t)wid * 128 + 2 * lane) = make_float2(ox, oy);
}

// ---------------- Gather-accumulate, layer 2 (final output) ----------------

__global__ __launch_bounds__(256) void k_gather2(const int* __restrict__ row_start,
                                                 const int* __restrict__ csr_src,
                                                 const float* __restrict__ feat,
                                                 const float* __restrict__ alpha,
                                                 const float* __restrict__ rden,
                                                 const float* __restrict__ bias,
                                                 float* __restrict__ out, int n) {
    int wid = (blockIdx.x * blockDim.x + threadIdx.x) >> 6;
    int lane = threadIdx.x & 63;
    if (wid >= n) return;
    int start = row_start[wid], end = row_start[wid + 1];
    float a = 0.f;
    for (int slot = start; slot < end; ++slot) {
        int s = __builtin_amdgcn_readfirstlane(csr_src[slot]);
        float w = alpha[slot];   // uniform address -> broadcast load (NO int readfirstlane: it value-converts floats)
        float f = feat[(size_t)s * 64 + lane];
        a += w * f;
    }
    float rd = rden[wid];
    out[(size_t)wid * 64 + lane] = a * rd + bias[lane];
}

// ---------------- launch ----------------

extern "C" void kernel_launch(void* const* d_in, const int* in_sizes, int n_in,
                              void* d_out, int out_size, void* d_ws, size_t ws_size,
                              hipStream_t stream) {
    const float* features = (const float*)d_in[0];
    const int* src = (const int*)d_in[1];
    const int* dst = (const int*)d_in[2];
    const float* fc1_w = (const float*)d_in[3];
    const float* attn_l1 = (const float*)d_in[4];
    const float* attn_r1 = (const float*)d_in[5];
    const float* bias1 = (const float*)d_in[6];
    const float* fc2_w = (const float*)d_in[7];
    const float* attn_l2 = (const float*)d_in[8];
    const float* attn_r2 = (const float*)d_in[9];
    const float* bias2 = (const float*)d_in[10];
    const int N = in_sizes[0] / 128;
    const int E = in_sizes[1];

    char* ws = (char*)d_ws;
    size_t off = 0;
    auto alloc = [&](size_t bytes) {
        void* p = ws + off;
        off = (off + bytes + 255) & ~(size_t)255;
        return p;
    };
    // persistent
    int* cnt = (int*)alloc((size_t)N * 4);
    int* fill = (int*)alloc((size_t)N * 4);
    int* row_start = (int*)alloc((size_t)(N + 1) * 4);
    int* partials = (int*)alloc(1024 * 4);
    int* csr_src = (int*)alloc((size_t)E * 4);
    float* x2 = (float*)alloc((size_t)N * 128 * 4);
    // layer-1 region (reused by layer 2 after k_gather1 completes)
    size_t l1_off = off;
    float* feat1 = (float*)alloc((size_t)N * 128 * 4);   // 51.2 MB
    float* el1 = (float*)alloc((size_t)N * 4 * 4);
    float* er1 = (float*)alloc((size_t)N * 4 * 4);
    float* alpha1 = (float*)alloc((size_t)E * 4 * 4);    // 25.6 MB
    float* rden1 = (float*)alloc((size_t)N * 4 * 4);
    // layer-2 aliases into layer-1 region (feat1 is dead after k_gather1)
    off = l1_off;
    float* feat2 = (float*)alloc((size_t)N * 64 * 4);    // 25.6 MB
    float* el2 = (float*)alloc((size_t)N * 4);
    float* er2 = (float*)alloc((size_t)N * 4);
    float* alpha2 = (float*)alloc((size_t)E * 4);        // 6.4 MB
    float* rden2 = (float*)alloc((size_t)N * 4);

    hipMemsetAsync(cnt, 0, (size_t)N * 4, stream);
    hipMemsetAsync(fill, 0, (size_t)N * 4, stream);

    k_count<<<(E + 255) / 256, 256, 0, stream>>>(dst, cnt, E);
    int nb = (N + 1023) / 1024;
    k_scan_local<<<nb, 256, 0, stream>>>(cnt, row_start, partials, N);
    k_scan_partials<<<1, 256, 0, stream>>>(partials, nb);
    k_scan_add<<<(N + 255) / 256, 256, 0, stream>>>(row_start, partials, N, E);
    k_scatter<<<(E + 255) / 256, 256, 0, stream>>>(src, dst, row_start, fill, csr_src, E);

    int nwave = (N + 3) / 4;
    k_gemm1<<<(N + 63) / 64, 256, 0, stream>>>(features, fc1_w, attn_l1, attn_r1, feat1, el1, er1, N);
    k_attn_w1<<<nwave, 256, 0, stream>>>(row_start, csr_src, el1, er1, alpha1, rden1, N);
    k_gather1<<<nwave, 256, 0, stream>>>(row_start, csr_src, feat1, alpha1, rden1, bias1, x2, N);
    k_gemm2<<<(N + 63) / 64, 256, 0, stream>>>(x2, fc2_w, attn_l2, attn_r2, feat2, el2, er2, N);
    k_attn_w2<<<nwave, 256, 0, stream>>>(row_start, csr_src, el2, er2, alpha2, rden2, N);
    k_gather2<<<nwave, 256, 0, stream>>>(row_start, csr_src, feat2, alpha2, rden2, bias2, (float*)d_out, N);
}

// Round 4
// 540.034 us; speedup vs baseline: 1.3038x; 1.3038x over previous
//
#include <hip/hip_runtime.h>
#include <math.h>

// ---------------- CSR build ----------------

__global__ __launch_bounds__(256) void k_count(const int* __restrict__ dst,
                                               int* __restrict__ cnt, int e) {
    int i = blockIdx.x * 256 + threadIdx.x;
    if (i < e) atomicAdd(&cnt[dst[i]], 1);
}

__global__ __launch_bounds__(256) void k_scan_local(const int* __restrict__ cnt,
                                                    int* __restrict__ row_start,
                                                    int* __restrict__ partials, int n) {
    __shared__ int sdata[256];
    int tid = threadIdx.x;
    int base = blockIdx.x * 1024 + tid * 4;
    int v0 = (base + 0 < n) ? cnt[base + 0] : 0;
    int v1 = (base + 1 < n) ? cnt[base + 1] : 0;
    int v2 = (base + 2 < n) ? cnt[base + 2] : 0;
    int v3 = (base + 3 < n) ? cnt[base + 3] : 0;
    int s = v0 + v1 + v2 + v3;
    sdata[tid] = s;
    __syncthreads();
    for (int off = 1; off < 256; off <<= 1) {
        int y = (tid >= off) ? sdata[tid - off] : 0;
        __syncthreads();
        sdata[tid] += y;
        __syncthreads();
    }
    int run = sdata[tid] - s;
    if (base + 0 < n) row_start[base + 0] = run;
    run += v0;
    if (base + 1 < n) row_start[base + 1] = run;
    run += v1;
    if (base + 2 < n) row_start[base + 2] = run;
    run += v2;
    if (base + 3 < n) row_start[base + 3] = run;
    if (tid == 255) partials[blockIdx.x] = sdata[255];
}

__global__ __launch_bounds__(256) void k_scan_partials(int* partials, int nb) {
    __shared__ int sdata[256];
    int tid = threadIdx.x;
    int v = (tid < nb) ? partials[tid] : 0;
    sdata[tid] = v;
    __syncthreads();
    for (int off = 1; off < 256; off <<= 1) {
        int y = (tid >= off) ? sdata[tid - off] : 0;
        __syncthreads();
        sdata[tid] += y;
        __syncthreads();
    }
    if (tid < nb) partials[tid] = sdata[tid] - v;
}

__global__ __launch_bounds__(256) void k_scan_add(int* __restrict__ row_start,
                                                  const int* __restrict__ partials,
                                                  int n, int total) {
    int i = blockIdx.x * 256 + threadIdx.x;
    if (i < n) row_start[i] += partials[i >> 10];
    if (i == 0) row_start[n] = total;
}

__global__ __launch_bounds__(256) void k_scatter(const int* __restrict__ src,
                                                 const int* __restrict__ dst,
                                                 const int* __restrict__ row_start,
                                                 int* __restrict__ fill,
                                                 int* __restrict__ csr_src, int e) {
    int i = blockIdx.x * 256 + threadIdx.x;
    if (i < e) {
        int d = dst[i];
        int pos = row_start[d] + atomicAdd(&fill[d], 1);
        csr_src[pos] = src[i];
    }
}

// ---------------- Layer 1 GEMM: [N,128] @ [128,128] + fused el/er ----------------
// split-K staging of W (2 x 32KB) -> 66KB LDS -> 2 blocks/CU.

__global__ __launch_bounds__(256) void k_gemm1(const float* __restrict__ X,
                                               const float* __restrict__ W,
                                               const float* __restrict__ attn_l,
                                               const float* __restrict__ attn_r,
                                               float* __restrict__ feat,
                                               float* __restrict__ el,
                                               float* __restrict__ er, int n) {
    __shared__ float sW[64 * 128];   // one K-half of W
    __shared__ float sX[64 * 132];
    int t = threadIdx.x;
    int node0 = blockIdx.x * 64;
    {
        const float4* Xv = (const float4*)X;
        for (int i = t; i < 64 * 32; i += 256) {
            int r = i >> 5, q = i & 31;
            int node = node0 + r;
            float4 val = make_float4(0.f, 0.f, 0.f, 0.f);
            if (node < n) val = Xv[(size_t)node * 32 + q];
            *(float4*)(sX + r * 132 + q * 4) = val;
        }
    }
    {
        const float4* Wv = (const float4*)W;   // rows 0..63
        float4* sWv = (float4*)sW;
#pragma unroll
        for (int i = 0; i < 8; ++i) sWv[t + i * 256] = Wv[t + i * 256];
    }
    __syncthreads();
    int tr = t >> 4, tc = t & 15;
    float acc[4][8] = {};
    for (int k = 0; k < 64; ++k) {
        float4 w0 = *(const float4*)(sW + k * 128 + tc * 8);
        float4 w1 = *(const float4*)(sW + k * 128 + tc * 8 + 4);
#pragma unroll
        for (int i = 0; i < 4; ++i) {
            float xk = sX[(tr + 16 * i) * 132 + k];
            acc[i][0] += xk * w0.x; acc[i][1] += xk * w0.y;
            acc[i][2] += xk * w0.z; acc[i][3] += xk * w0.w;
            acc[i][4] += xk * w1.x; acc[i][5] += xk * w1.y;
            acc[i][6] += xk * w1.z; acc[i][7] += xk * w1.w;
        }
    }
    __syncthreads();
    {
        const float4* Wv = (const float4*)(W + 64 * 128);   // rows 64..127
        float4* sWv = (float4*)sW;
#pragma unroll
        for (int i = 0; i < 8; ++i) sWv[t + i * 256] = Wv[t + i * 256];
    }
    __syncthreads();
    for (int k = 0; k < 64; ++k) {
        float4 w0 = *(const float4*)(sW + k * 128 + tc * 8);
        float4 w1 = *(const float4*)(sW + k * 128 + tc * 8 + 4);
#pragma unroll
        for (int i = 0; i < 4; ++i) {
            float xk = sX[(tr + 16 * i) * 132 + (64 + k)];
            acc[i][0] += xk * w0.x; acc[i][1] += xk * w0.y;
            acc[i][2] += xk * w0.z; acc[i][3] += xk * w0.w;
            acc[i][4] += xk * w1.x; acc[i][5] += xk * w1.y;
            acc[i][6] += xk * w1.z; acc[i][7] += xk * w1.w;
        }
    }
    int h = tc >> 2;
    int dbase = (tc & 3) * 8;
    float al[8], ar[8];
#pragma unroll
    for (int j = 0; j < 8; ++j) {
        al[j] = attn_l[h * 32 + dbase + j];
        ar[j] = attn_r[h * 32 + dbase + j];
    }
#pragma unroll
    for (int i = 0; i < 4; ++i) {
        int node = node0 + tr + 16 * i;
        float pl = 0.f, pr = 0.f;
#pragma unroll
        for (int j = 0; j < 8; ++j) { pl += acc[i][j] * al[j]; pr += acc[i][j] * ar[j]; }
        pl += __shfl_xor(pl, 1); pl += __shfl_xor(pl, 2);
        pr += __shfl_xor(pr, 1); pr += __shfl_xor(pr, 2);
        if (node < n) {
            float4 f0 = make_float4(acc[i][0], acc[i][1], acc[i][2], acc[i][3]);
            float4 f1 = make_float4(acc[i][4], acc[i][5], acc[i][6], acc[i][7]);
            *(float4*)(feat + (size_t)node * 128 + tc * 8) = f0;
            *(float4*)(feat + (size_t)node * 128 + tc * 8 + 4) = f1;
            if ((tc & 3) == 0) { el[node * 4 + h] = pl; er[node * 4 + h] = pr; }
        }
    }
}

// ---------------- Layer 2 GEMM: [N,128] @ [128,64] + fused el/er (H=1) ----------------

__global__ __launch_bounds__(256) void k_gemm2(const float* __restrict__ X,
                                               const float* __restrict__ W,
                                               const float* __restrict__ attn_l,
                                               const float* __restrict__ attn_r,
                                               float* __restrict__ feat,
                                               float* __restrict__ el,
                                               float* __restrict__ er, int n) {
    __shared__ float sW[128 * 64];
    __shared__ float sX[64 * 132];
    int t = threadIdx.x;
    {
        const float4* Wv = (const float4*)W;
        float4* sWv = (float4*)sW;
#pragma unroll
        for (int i = 0; i < 8; ++i) sWv[t + i * 256] = Wv[t + i * 256];
    }
    int node0 = blockIdx.x * 64;
    {
        const float4* Xv = (const float4*)X;
        for (int i = t; i < 64 * 32; i += 256) {
            int r = i >> 5, q = i & 31;
            int node = node0 + r;
            float4 val = make_float4(0.f, 0.f, 0.f, 0.f);
            if (node < n) val = Xv[(size_t)node * 32 + q];
            *(float4*)(sX + r * 132 + q * 4) = val;
        }
    }
    __syncthreads();
    int tr = t >> 3, tc = t & 7;
    float acc[2][8] = {};
    for (int k = 0; k < 128; ++k) {
        float4 w0 = *(const float4*)(sW + k * 64 + tc * 8);
        float4 w1 = *(const float4*)(sW + k * 64 + tc * 8 + 4);
#pragma unroll
        for (int i = 0; i < 2; ++i) {
            float xk = sX[(tr + 32 * i) * 132 + k];
            acc[i][0] += xk * w0.x; acc[i][1] += xk * w0.y;
            acc[i][2] += xk * w0.z; acc[i][3] += xk * w0.w;
            acc[i][4] += xk * w1.x; acc[i][5] += xk * w1.y;
            acc[i][6] += xk * w1.z; acc[i][7] += xk * w1.w;
        }
    }
    float al[8], ar[8];
#pragma unroll
    for (int j = 0; j < 8; ++j) { al[j] = attn_l[tc * 8 + j]; ar[j] = attn_r[tc * 8 + j]; }
#pragma unroll
    for (int i = 0; i < 2; ++i) {
        int node = node0 + tr + 32 * i;
        float pl = 0.f, pr = 0.f;
#pragma unroll
        for (int j = 0; j < 8; ++j) { pl += acc[i][j] * al[j]; pr += acc[i][j] * ar[j]; }
        pl += __shfl_xor(pl, 1); pl += __shfl_xor(pl, 2); pl += __shfl_xor(pl, 4);
        pr += __shfl_xor(pr, 1); pr += __shfl_xor(pr, 2); pr += __shfl_xor(pr, 4);
        if (node < n) {
            float4 f0 = make_float4(acc[i][0], acc[i][1], acc[i][2], acc[i][3]);
            float4 f1 = make_float4(acc[i][4], acc[i][5], acc[i][6], acc[i][7]);
            *(float4*)(feat + (size_t)node * 64 + tc * 8) = f0;
            *(float4*)(feat + (size_t)node * 64 + tc * 8 + 4) = f1;
            if (tc == 0) { el[node] = pl; er[node] = pr; }
        }
    }
}

// ---------------- Attention weights, layer 1 (H=4) ----------------

__global__ __launch_bounds__(256) void k_attn_w1(const int* __restrict__ row_start,
                                                 const int* __restrict__ csr_src,
                                                 const float* __restrict__ el,
                                                 const float* __restrict__ er,
                                                 float* __restrict__ alpha,
                                                 float* __restrict__ rden, int n) {
    int wid = (blockIdx.x * blockDim.x + threadIdx.x) >> 6;
    int lane = threadIdx.x & 63;
    if (wid >= n) return;
    int start = row_start[wid], end = row_start[wid + 1];
    float4 er4 = *(const float4*)(er + wid * 4);
    float m0 = -INFINITY, m1 = -INFINITY, m2 = -INFINITY, m3 = -INFINITY;
    for (int slot = start + lane; slot < end; slot += 64) {
        int s = csr_src[slot];
        float4 e4 = *(const float4*)(el + s * 4);
        float e0 = e4.x + er4.x, e1 = e4.y + er4.y, e2 = e4.z + er4.z, e3 = e4.w + er4.w;
        e0 = (e0 > 0.f) ? e0 : 0.2f * e0;
        e1 = (e1 > 0.f) ? e1 : 0.2f * e1;
        e2 = (e2 > 0.f) ? e2 : 0.2f * e2;
        e3 = (e3 > 0.f) ? e3 : 0.2f * e3;
        m0 = fmaxf(m0, e0); m1 = fmaxf(m1, e1); m2 = fmaxf(m2, e2); m3 = fmaxf(m3, e3);
    }
#pragma unroll
    for (int off = 1; off < 64; off <<= 1) {
        m0 = fmaxf(m0, __shfl_xor(m0, off));
        m1 = fmaxf(m1, __shfl_xor(m1, off));
        m2 = fmaxf(m2, __shfl_xor(m2, off));
        m3 = fmaxf(m3, __shfl_xor(m3, off));
    }
    float d0 = 0.f, d1 = 0.f, d2 = 0.f, d3 = 0.f;
    for (int slot = start + lane; slot < end; slot += 64) {
        int s = csr_src[slot];
        float4 e4 = *(const float4*)(el + s * 4);
        float e0 = e4.x + er4.x, e1 = e4.y + er4.y, e2 = e4.z + er4.z, e3 = e4.w + er4.w;
        e0 = (e0 > 0.f) ? e0 : 0.2f * e0;
        e1 = (e1 > 0.f) ? e1 : 0.2f * e1;
        e2 = (e2 > 0.f) ? e2 : 0.2f * e2;
        e3 = (e3 > 0.f) ? e3 : 0.2f * e3;
        float w0 = __expf(e0 - m0), w1 = __expf(e1 - m1);
        float w2 = __expf(e2 - m2), w3 = __expf(e3 - m3);
        d0 += w0; d1 += w1; d2 += w2; d3 += w3;
        *(float4*)(alpha + (size_t)slot * 4) = make_float4(w0, w1, w2, w3);
    }
#pragma unroll
    for (int off = 1; off < 64; off <<= 1) {
        d0 += __shfl_xor(d0, off);
        d1 += __shfl_xor(d1, off);
        d2 += __shfl_xor(d2, off);
        d3 += __shfl_xor(d3, off);
    }
    if (lane == 0) {
        float4 rd;
        rd.x = (d0 > 0.f) ? 1.f / d0 : 0.f;
        rd.y = (d1 > 0.f) ? 1.f / d1 : 0.f;
        rd.z = (d2 > 0.f) ? 1.f / d2 : 0.f;
        rd.w = (d3 > 0.f) ? 1.f / d3 : 0.f;
        *(float4*)(rden + wid * 4) = rd;
    }
}

// ---------------- Attention weights, layer 2 (H=1) ----------------

__global__ __launch_bounds__(256) void k_attn_w2(const int* __restrict__ row_start,
                                                 const int* __restrict__ csr_src,
                                                 const float* __restrict__ el,
                                                 const float* __restrict__ er,
                                                 float* __restrict__ alpha,
                                                 float* __restrict__ rden, int n) {
    int wid = (blockIdx.x * blockDim.x + threadIdx.x) >> 6;
    int lane = threadIdx.x & 63;
    if (wid >= n) return;
    int start = row_start[wid], end = row_start[wid + 1];
    float erv = er[wid];
    float m = -INFINITY;
    for (int slot = start + lane; slot < end; slot += 64) {
        int s = csr_src[slot];
        float e = el[s] + erv;
        e = (e > 0.f) ? e : 0.2f * e;
        m = fmaxf(m, e);
    }
#pragma unroll
    for (int off = 1; off < 64; off <<= 1) m = fmaxf(m, __shfl_xor(m, off));
    float d = 0.f;
    for (int slot = start + lane; slot < end; slot += 64) {
        int s = csr_src[slot];
        float e = el[s] + erv;
        e = (e > 0.f) ? e : 0.2f * e;
        float w = __expf(e - m);
        d += w;
        alpha[slot] = w;
    }
#pragma unroll
    for (int off = 1; off < 64; off <<= 1) d += __shfl_xor(d, off);
    if (lane == 0) rden[wid] = (d > 0.f) ? 1.f / d : 0.f;
}

// ---------------- Gather-accumulate, layer 1 ----------------
// wave per node; 4 edge-subgroups x 16 dim-lanes; dim-lane owns 8 dims (2x float4).
// Unroll-by-2 -> up to 8 edge rows (4KB) in flight per wave.

__global__ __launch_bounds__(256) void k_gather1(const int* __restrict__ row_start,
                                                 const int* __restrict__ csr_src,
                                                 const float* __restrict__ feat,
                                                 const float* __restrict__ alpha,
                                                 const float* __restrict__ rden,
                                                 const float* __restrict__ bias,
                                                 float* __restrict__ xout, int n) {
    int wid = (blockIdx.x * blockDim.x + threadIdx.x) >> 6;
    int lane = threadIdx.x & 63;
    if (wid >= n) return;
    int g = lane >> 4;    // edge subgroup 0..3
    int dl = lane & 15;   // dims 8*dl .. 8*dl+7
    int h = dl >> 2;      // head
    int start = row_start[wid], end = row_start[wid + 1];
    float4 A0 = make_float4(0.f, 0.f, 0.f, 0.f);
    float4 A1 = make_float4(0.f, 0.f, 0.f, 0.f);
    int slot = start + g;
    for (; slot + 4 < end; slot += 8) {
        int sA = csr_src[slot];
        int sB = csr_src[slot + 4];
        float wA = alpha[(size_t)slot * 4 + h];
        float wB = alpha[(size_t)(slot + 4) * 4 + h];
        const float* pA = feat + (size_t)sA * 128 + 8 * dl;
        const float* pB = feat + (size_t)sB * 128 + 8 * dl;
        float4 fA0 = *(const float4*)pA;
        float4 fA1 = *(const float4*)(pA + 4);
        float4 fB0 = *(const float4*)pB;
        float4 fB1 = *(const float4*)(pB + 4);
        A0.x += wA * fA0.x; A0.y += wA * fA0.y; A0.z += wA * fA0.z; A0.w += wA * fA0.w;
        A1.x += wA * fA1.x; A1.y += wA * fA1.y; A1.z += wA * fA1.z; A1.w += wA * fA1.w;
        A0.x += wB * fB0.x; A0.y += wB * fB0.y; A0.z += wB * fB0.z; A0.w += wB * fB0.w;
        A1.x += wB * fB1.x; A1.y += wB * fB1.y; A1.z += wB * fB1.z; A1.w += wB * fB1.w;
    }
    if (slot < end) {
        int s = csr_src[slot];
        float w = alpha[(size_t)slot * 4 + h];
        const float* p = feat + (size_t)s * 128 + 8 * dl;
        float4 f0 = *(const float4*)p;
        float4 f1 = *(const float4*)(p + 4);
        A0.x += w * f0.x; A0.y += w * f0.y; A0.z += w * f0.z; A0.w += w * f0.w;
        A1.x += w * f1.x; A1.y += w * f1.y; A1.z += w * f1.z; A1.w += w * f1.w;
    }
#pragma unroll
    for (int off = 16; off < 64; off <<= 1) {
        A0.x += __shfl_xor(A0.x, off); A0.y += __shfl_xor(A0.y, off);
        A0.z += __shfl_xor(A0.z, off); A0.w += __shfl_xor(A0.w, off);
        A1.x += __shfl_xor(A1.x, off); A1.y += __shfl_xor(A1.y, off);
        A1.z += __shfl_xor(A1.z, off); A1.w += __shfl_xor(A1.w, off);
    }
    if (g == 0) {
        float rd = rden[wid * 4 + h];
        const float* bp = bias + 8 * dl;
        float4 b0 = *(const float4*)bp;
        float4 b1 = *(const float4*)(bp + 4);
        float o[8];
        o[0] = A0.x * rd + b0.x; o[1] = A0.y * rd + b0.y;
        o[2] = A0.z * rd + b0.z; o[3] = A0.w * rd + b0.w;
        o[4] = A1.x * rd + b1.x; o[5] = A1.y * rd + b1.y;
        o[6] = A1.z * rd + b1.z; o[7] = A1.w * rd + b1.w;
#pragma unroll
        for (int j = 0; j < 8; ++j) o[j] = (o[j] > 0.f) ? o[j] : (__expf(o[j]) - 1.f);
        float* xp = xout + (size_t)wid * 128 + 8 * dl;
        *(float4*)xp = make_float4(o[0], o[1], o[2], o[3]);
        *(float4*)(xp + 4) = make_float4(o[4], o[5], o[6], o[7]);
    }
}

// ---------------- Gather-accumulate, layer 2 (final output) ----------------
// 4 edge-subgroups x 16 dim-lanes; dim-lane owns 4 dims (float4).

__global__ __launch_bounds__(256) void k_gather2(const int* __restrict__ row_start,
                                                 const int* __restrict__ csr_src,
                                                 const float* __restrict__ feat,
                                                 const float* __restrict__ alpha,
                                                 const float* __restrict__ rden,
                                                 const float* __restrict__ bias,
                                                 float* __restrict__ out, int n) {
    int wid = (blockIdx.x * blockDim.x + threadIdx.x) >> 6;
    int lane = threadIdx.x & 63;
    if (wid >= n) return;
    int g = lane >> 4;
    int dl = lane & 15;   // dims 4*dl .. 4*dl+3
    int start = row_start[wid], end = row_start[wid + 1];
    float4 A = make_float4(0.f, 0.f, 0.f, 0.f);
    int slot = start + g;
    for (; slot + 4 < end; slot += 8) {
        int sA = csr_src[slot];
        int sB = csr_src[slot + 4];
        float wA = alpha[slot];
        float wB = alpha[slot + 4];
        float4 fA = *(const float4*)(feat + (size_t)sA * 64 + 4 * dl);
        float4 fB = *(const float4*)(feat + (size_t)sB * 64 + 4 * dl);
        A.x += wA * fA.x; A.y += wA * fA.y; A.z += wA * fA.z; A.w += wA * fA.w;
        A.x += wB * fB.x; A.y += wB * fB.y; A.z += wB * fB.z; A.w += wB * fB.w;
    }
    if (slot < end) {
        int s = csr_src[slot];
        float w = alpha[slot];
        float4 f = *(const float4*)(feat + (size_t)s * 64 + 4 * dl);
        A.x += w * f.x; A.y += w * f.y; A.z += w * f.z; A.w += w * f.w;
    }
#pragma unroll
    for (int off = 16; off < 64; off <<= 1) {
        A.x += __shfl_xor(A.x, off); A.y += __shfl_xor(A.y, off);
        A.z += __shfl_xor(A.z, off); A.w += __shfl_xor(A.w, off);
    }
    if (g == 0) {
        float rd = rden[wid];
        float4 b = *(const float4*)(bias + 4 * dl);
        float4 o;
        o.x = A.x * rd + b.x; o.y = A.y * rd + b.y;
        o.z = A.z * rd + b.z; o.w = A.w * rd + b.w;
        *(float4*)(out + (size_t)wid * 64 + 4 * dl) = o;
    }
}

// ---------------- launch ----------------

extern "C" void kernel_launch(void* const* d_in, const int* in_sizes, int n_in,
                              void* d_out, int out_size, void* d_ws, size_t ws_size,
                              hipStream_t stream) {
    const float* features = (const float*)d_in[0];
    const int* src = (const int*)d_in[1];
    const int* dst = (const int*)d_in[2];
    const float* fc1_w = (const float*)d_in[3];
    const float* attn_l1 = (const float*)d_in[4];
    const float* attn_r1 = (const float*)d_in[5];
    const float* bias1 = (const float*)d_in[6];
    const float* fc2_w = (const float*)d_in[7];
    const float* attn_l2 = (const float*)d_in[8];
    const float* attn_r2 = (const float*)d_in[9];
    const float* bias2 = (const float*)d_in[10];
    const int N = in_sizes[0] / 128;
    const int E = in_sizes[1];

    char* ws = (char*)d_ws;
    size_t off = 0;
    auto alloc = [&](size_t bytes) {
        void* p = ws + off;
        off = (off + bytes + 255) & ~(size_t)255;
        return p;
    };
    // persistent
    int* cnt = (int*)alloc((size_t)N * 4);
    int* fill = (int*)alloc((size_t)N * 4);
    int* row_start = (int*)alloc((size_t)(N + 1) * 4);
    int* partials = (int*)alloc(1024 * 4);
    int* csr_src = (int*)alloc((size_t)E * 4);
    float* x2 = (float*)alloc((size_t)N * 128 * 4);
    // layer-1 region (reused by layer 2 after k_gather1 completes)
    size_t l1_off = off;
    float* feat1 = (float*)alloc((size_t)N * 128 * 4);
    float* el1 = (float*)alloc((size_t)N * 4 * 4);
    float* er1 = (float*)alloc((size_t)N * 4 * 4);
    float* alpha1 = (float*)alloc((size_t)E * 4 * 4);
    float* rden1 = (float*)alloc((size_t)N * 4 * 4);
    // layer-2 aliases into layer-1 region (feat1 dead after k_gather1)
    off = l1_off;
    float* feat2 = (float*)alloc((size_t)N * 64 * 4);
    float* el2 = (float*)alloc((size_t)N * 4);
    float* er2 = (float*)alloc((size_t)N * 4);
    float* alpha2 = (float*)alloc((size_t)E * 4);
    float* rden2 = (float*)alloc((size_t)N * 4);

    hipMemsetAsync(cnt, 0, (size_t)N * 4, stream);
    hipMemsetAsync(fill, 0, (size_t)N * 4, stream);

    k_count<<<(E + 255) / 256, 256, 0, stream>>>(dst, cnt, E);
    int nb = (N + 1023) / 1024;
    k_scan_local<<<nb, 256, 0, stream>>>(cnt, row_start, partials, N);
    k_scan_partials<<<1, 256, 0, stream>>>(partials, nb);
    k_scan_add<<<(N + 255) / 256, 256, 0, stream>>>(row_start, partials, N, E);
    k_scatter<<<(E + 255) / 256, 256, 0, stream>>>(src, dst, row_start, fill, csr_src, E);

    int nwave = (N + 3) / 4;
    k_gemm1<<<(N + 63) / 64, 256, 0, stream>>>(features, fc1_w, attn_l1, attn_r1, feat1, el1, er1, N);
    k_attn_w1<<<nwave, 256, 0, stream>>>(row_start, csr_src, el1, er1, alpha1, rden1, N);
    k_gather1<<<nwave, 256, 0, stream>>>(row_start, csr_src, feat1, alpha1, rden1, bias1, x2, N);
    k_gemm2<<<(N + 63) / 64, 256, 0, stream>>>(x2, fc2_w, attn_l2, attn_r2, feat2, el2, er2, N);
    k_attn_w2<<<nwave, 256, 0, stream>>>(row_start, csr_src, el2, er2, alpha2, rden2, N);
    k_gather2<<<nwave, 256, 0, stream>>>(row_start, csr_src, feat2, alpha2, rden2, bias2, (float*)d_out, N);
}

// Round 5
// 479.186 us; speedup vs baseline: 1.4694x; 1.1270x over previous
//
#include <hip/hip_runtime.h>
#include <math.h>

// ---------------- helpers ----------------

__device__ __forceinline__ unsigned int packbf2(float a, float b) {
    unsigned int ua = __float_as_uint(a);
    ua = (ua + 0x7FFFu + ((ua >> 16) & 1u)) >> 16;
    unsigned int ub = __float_as_uint(b);
    ub = (ub + 0x7FFFu + ((ub >> 16) & 1u)) & 0xFFFF0000u;
    return ua | ub;
}

__device__ __forceinline__ void bf2_fma(unsigned int u, float w, float& a0, float& a1) {
    a0 += w * __uint_as_float(u << 16);
    a1 += w * __uint_as_float(u & 0xFFFF0000u);
}

// ---------------- CSR build ----------------

__global__ __launch_bounds__(256) void k_count(const int* __restrict__ dst,
                                               int* __restrict__ cnt, int e) {
    int i = blockIdx.x * 256 + threadIdx.x;
    if (i < e) atomicAdd(&cnt[dst[i]], 1);
}

__global__ __launch_bounds__(256) void k_scan_local(const int* __restrict__ cnt,
                                                    int* __restrict__ row_start,
                                                    int* __restrict__ partials, int n) {
    __shared__ int sdata[256];
    int tid = threadIdx.x;
    int base = blockIdx.x * 1024 + tid * 4;
    int v0 = (base + 0 < n) ? cnt[base + 0] : 0;
    int v1 = (base + 1 < n) ? cnt[base + 1] : 0;
    int v2 = (base + 2 < n) ? cnt[base + 2] : 0;
    int v3 = (base + 3 < n) ? cnt[base + 3] : 0;
    int s = v0 + v1 + v2 + v3;
    sdata[tid] = s;
    __syncthreads();
    for (int off = 1; off < 256; off <<= 1) {
        int y = (tid >= off) ? sdata[tid - off] : 0;
        __syncthreads();
        sdata[tid] += y;
        __syncthreads();
    }
    int run = sdata[tid] - s;
    if (base + 0 < n) row_start[base + 0] = run;
    run += v0;
    if (base + 1 < n) row_start[base + 1] = run;
    run += v1;
    if (base + 2 < n) row_start[base + 2] = run;
    run += v2;
    if (base + 3 < n) row_start[base + 3] = run;
    if (tid == 255) partials[blockIdx.x] = sdata[255];
}

__global__ __launch_bounds__(256) void k_scan_partials(int* partials, int nb) {
    __shared__ int sdata[256];
    int tid = threadIdx.x;
    int v = (tid < nb) ? partials[tid] : 0;
    sdata[tid] = v;
    __syncthreads();
    for (int off = 1; off < 256; off <<= 1) {
        int y = (tid >= off) ? sdata[tid - off] : 0;
        __syncthreads();
        sdata[tid] += y;
        __syncthreads();
    }
    if (tid < nb) partials[tid] = sdata[tid] - v;
}

__global__ __launch_bounds__(256) void k_scan_add(int* __restrict__ row_start,
                                                  const int* __restrict__ partials,
                                                  int n, int total) {
    int i = blockIdx.x * 256 + threadIdx.x;
    if (i < n) row_start[i] += partials[i >> 10];
    if (i == 0) row_start[n] = total;
}

__global__ __launch_bounds__(256) void k_scatter(const int* __restrict__ src,
                                                 const int* __restrict__ dst,
                                                 const int* __restrict__ row_start,
                                                 int* __restrict__ fill,
                                                 int* __restrict__ csr_src, int e) {
    int i = blockIdx.x * 256 + threadIdx.x;
    if (i < e) {
        int d = dst[i];
        int pos = row_start[d] + atomicAdd(&fill[d], 1);
        csr_src[pos] = src[i];
    }
}

// ---------------- Layer 1 GEMM: [N,128] @ [128,128] + fused el/er, bf16 feat out ----------------

__global__ __launch_bounds__(256) void k_gemm1(const float* __restrict__ X,
                                               const float* __restrict__ W,
                                               const float* __restrict__ attn_l,
                                               const float* __restrict__ attn_r,
                                               unsigned short* __restrict__ feat,
                                               float* __restrict__ el,
                                               float* __restrict__ er, int n) {
    __shared__ float sW[64 * 128];   // one K-half of W
    __shared__ float sX[64 * 132];
    int t = threadIdx.x;
    int node0 = blockIdx.x * 64;
    {
        const float4* Xv = (const float4*)X;
        for (int i = t; i < 64 * 32; i += 256) {
            int r = i >> 5, q = i & 31;
            int node = node0 + r;
            float4 val = make_float4(0.f, 0.f, 0.f, 0.f);
            if (node < n) val = Xv[(size_t)node * 32 + q];
            *(float4*)(sX + r * 132 + q * 4) = val;
        }
    }
    {
        const float4* Wv = (const float4*)W;   // rows 0..63
        float4* sWv = (float4*)sW;
#pragma unroll
        for (int i = 0; i < 8; ++i) sWv[t + i * 256] = Wv[t + i * 256];
    }
    __syncthreads();
    int tr = t >> 4, tc = t & 15;
    float acc[4][8] = {};
    for (int k = 0; k < 64; ++k) {
        float4 w0 = *(const float4*)(sW + k * 128 + tc * 8);
        float4 w1 = *(const float4*)(sW + k * 128 + tc * 8 + 4);
#pragma unroll
        for (int i = 0; i < 4; ++i) {
            float xk = sX[(tr + 16 * i) * 132 + k];
            acc[i][0] += xk * w0.x; acc[i][1] += xk * w0.y;
            acc[i][2] += xk * w0.z; acc[i][3] += xk * w0.w;
            acc[i][4] += xk * w1.x; acc[i][5] += xk * w1.y;
            acc[i][6] += xk * w1.z; acc[i][7] += xk * w1.w;
        }
    }
    __syncthreads();
    {
        const float4* Wv = (const float4*)(W + 64 * 128);   // rows 64..127
        float4* sWv = (float4*)sW;
#pragma unroll
        for (int i = 0; i < 8; ++i) sWv[t + i * 256] = Wv[t + i * 256];
    }
    __syncthreads();
    for (int k = 0; k < 64; ++k) {
        float4 w0 = *(const float4*)(sW + k * 128 + tc * 8);
        float4 w1 = *(const float4*)(sW + k * 128 + tc * 8 + 4);
#pragma unroll
        for (int i = 0; i < 4; ++i) {
            float xk = sX[(tr + 16 * i) * 132 + (64 + k)];
            acc[i][0] += xk * w0.x; acc[i][1] += xk * w0.y;
            acc[i][2] += xk * w0.z; acc[i][3] += xk * w0.w;
            acc[i][4] += xk * w1.x; acc[i][5] += xk * w1.y;
            acc[i][6] += xk * w1.z; acc[i][7] += xk * w1.w;
        }
    }
    int h = tc >> 2;
    int dbase = (tc & 3) * 8;
    float al[8], ar[8];
#pragma unroll
    for (int j = 0; j < 8; ++j) {
        al[j] = attn_l[h * 32 + dbase + j];
        ar[j] = attn_r[h * 32 + dbase + j];
    }
#pragma unroll
    for (int i = 0; i < 4; ++i) {
        int node = node0 + tr + 16 * i;
        float pl = 0.f, pr = 0.f;
#pragma unroll
        for (int j = 0; j < 8; ++j) { pl += acc[i][j] * al[j]; pr += acc[i][j] * ar[j]; }
        pl += __shfl_xor(pl, 1); pl += __shfl_xor(pl, 2);
        pr += __shfl_xor(pr, 1); pr += __shfl_xor(pr, 2);
        if (node < n) {
            uint4 pk;
            pk.x = packbf2(acc[i][0], acc[i][1]);
            pk.y = packbf2(acc[i][2], acc[i][3]);
            pk.z = packbf2(acc[i][4], acc[i][5]);
            pk.w = packbf2(acc[i][6], acc[i][7]);
            *(uint4*)(feat + (size_t)node * 128 + tc * 8) = pk;
            if ((tc & 3) == 0) { el[node * 4 + h] = pl; er[node * 4 + h] = pr; }
        }
    }
}

// ---------------- Layer 2 GEMM: [N,128] @ [128,64] + fused el/er (H=1), bf16 feat out ----------------

__global__ __launch_bounds__(256) void k_gemm2(const float* __restrict__ X,
                                               const float* __restrict__ W,
                                               const float* __restrict__ attn_l,
                                               const float* __restrict__ attn_r,
                                               unsigned short* __restrict__ feat,
                                               float* __restrict__ el,
                                               float* __restrict__ er, int n) {
    __shared__ float sW[128 * 64];
    __shared__ float sX[64 * 132];
    int t = threadIdx.x;
    {
        const float4* Wv = (const float4*)W;
        float4* sWv = (float4*)sW;
#pragma unroll
        for (int i = 0; i < 8; ++i) sWv[t + i * 256] = Wv[t + i * 256];
    }
    int node0 = blockIdx.x * 64;
    {
        const float4* Xv = (const float4*)X;
        for (int i = t; i < 64 * 32; i += 256) {
            int r = i >> 5, q = i & 31;
            int node = node0 + r;
            float4 val = make_float4(0.f, 0.f, 0.f, 0.f);
            if (node < n) val = Xv[(size_t)node * 32 + q];
            *(float4*)(sX + r * 132 + q * 4) = val;
        }
    }
    __syncthreads();
    int tr = t >> 3, tc = t & 7;
    float acc[2][8] = {};
    for (int k = 0; k < 128; ++k) {
        float4 w0 = *(const float4*)(sW + k * 64 + tc * 8);
        float4 w1 = *(const float4*)(sW + k * 64 + tc * 8 + 4);
#pragma unroll
        for (int i = 0; i < 2; ++i) {
            float xk = sX[(tr + 32 * i) * 132 + k];
            acc[i][0] += xk * w0.x; acc[i][1] += xk * w0.y;
            acc[i][2] += xk * w0.z; acc[i][3] += xk * w0.w;
            acc[i][4] += xk * w1.x; acc[i][5] += xk * w1.y;
            acc[i][6] += xk * w1.z; acc[i][7] += xk * w1.w;
        }
    }
    float al[8], ar[8];
#pragma unroll
    for (int j = 0; j < 8; ++j) { al[j] = attn_l[tc * 8 + j]; ar[j] = attn_r[tc * 8 + j]; }
#pragma unroll
    for (int i = 0; i < 2; ++i) {
        int node = node0 + tr + 32 * i;
        float pl = 0.f, pr = 0.f;
#pragma unroll
        for (int j = 0; j < 8; ++j) { pl += acc[i][j] * al[j]; pr += acc[i][j] * ar[j]; }
        pl += __shfl_xor(pl, 1); pl += __shfl_xor(pl, 2); pl += __shfl_xor(pl, 4);
        pr += __shfl_xor(pr, 1); pr += __shfl_xor(pr, 2); pr += __shfl_xor(pr, 4);
        if (node < n) {
            uint4 pk;
            pk.x = packbf2(acc[i][0], acc[i][1]);
            pk.y = packbf2(acc[i][2], acc[i][3]);
            pk.z = packbf2(acc[i][4], acc[i][5]);
            pk.w = packbf2(acc[i][6], acc[i][7]);
            *(uint4*)(feat + (size_t)node * 64 + tc * 8) = pk;
            if (tc == 0) { el[node] = pl; er[node] = pr; }
        }
    }
}

// ---------------- Attention weights, layer 1 (H=4) ----------------

__global__ __launch_bounds__(256) void k_attn_w1(const int* __restrict__ row_start,
                                                 const int* __restrict__ csr_src,
                                                 const float* __restrict__ el,
                                                 const float* __restrict__ er,
                                                 float* __restrict__ alpha,
                                                 float* __restrict__ rden, int n) {
    int wid = (blockIdx.x * blockDim.x + threadIdx.x) >> 6;
    int lane = threadIdx.x & 63;
    if (wid >= n) return;
    int start = row_start[wid], end = row_start[wid + 1];
    float4 er4 = *(const float4*)(er + wid * 4);
    float m0 = -INFINITY, m1 = -INFINITY, m2 = -INFINITY, m3 = -INFINITY;
    for (int slot = start + lane; slot < end; slot += 64) {
        int s = csr_src[slot];
        float4 e4 = *(const float4*)(el + s * 4);
        float e0 = e4.x + er4.x, e1 = e4.y + er4.y, e2 = e4.z + er4.z, e3 = e4.w + er4.w;
        e0 = (e0 > 0.f) ? e0 : 0.2f * e0;
        e1 = (e1 > 0.f) ? e1 : 0.2f * e1;
        e2 = (e2 > 0.f) ? e2 : 0.2f * e2;
        e3 = (e3 > 0.f) ? e3 : 0.2f * e3;
        m0 = fmaxf(m0, e0); m1 = fmaxf(m1, e1); m2 = fmaxf(m2, e2); m3 = fmaxf(m3, e3);
    }
#pragma unroll
    for (int off = 1; off < 64; off <<= 1) {
        m0 = fmaxf(m0, __shfl_xor(m0, off));
        m1 = fmaxf(m1, __shfl_xor(m1, off));
        m2 = fmaxf(m2, __shfl_xor(m2, off));
        m3 = fmaxf(m3, __shfl_xor(m3, off));
    }
    float d0 = 0.f, d1 = 0.f, d2 = 0.f, d3 = 0.f;
    for (int slot = start + lane; slot < end; slot += 64) {
        int s = csr_src[slot];
        float4 e4 = *(const float4*)(el + s * 4);
        float e0 = e4.x + er4.x, e1 = e4.y + er4.y, e2 = e4.z + er4.z, e3 = e4.w + er4.w;
        e0 = (e0 > 0.f) ? e0 : 0.2f * e0;
        e1 = (e1 > 0.f) ? e1 : 0.2f * e1;
        e2 = (e2 > 0.f) ? e2 : 0.2f * e2;
        e3 = (e3 > 0.f) ? e3 : 0.2f * e3;
        float w0 = __expf(e0 - m0), w1 = __expf(e1 - m1);
        float w2 = __expf(e2 - m2), w3 = __expf(e3 - m3);
        d0 += w0; d1 += w1; d2 += w2; d3 += w3;
        *(float4*)(alpha + (size_t)slot * 4) = make_float4(w0, w1, w2, w3);
    }
#pragma unroll
    for (int off = 1; off < 64; off <<= 1) {
        d0 += __shfl_xor(d0, off);
        d1 += __shfl_xor(d1, off);
        d2 += __shfl_xor(d2, off);
        d3 += __shfl_xor(d3, off);
    }
    if (lane == 0) {
        float4 rd;
        rd.x = (d0 > 0.f) ? 1.f / d0 : 0.f;
        rd.y = (d1 > 0.f) ? 1.f / d1 : 0.f;
        rd.z = (d2 > 0.f) ? 1.f / d2 : 0.f;
        rd.w = (d3 > 0.f) ? 1.f / d3 : 0.f;
        *(float4*)(rden + wid * 4) = rd;
    }
}

// ---------------- Attention weights, layer 2 (H=1) ----------------

__global__ __launch_bounds__(256) void k_attn_w2(const int* __restrict__ row_start,
                                                 const int* __restrict__ csr_src,
                                                 const float* __restrict__ el,
                                                 const float* __restrict__ er,
                                                 float* __restrict__ alpha,
                                                 float* __restrict__ rden, int n) {
    int wid = (blockIdx.x * blockDim.x + threadIdx.x) >> 6;
    int lane = threadIdx.x & 63;
    if (wid >= n) return;
    int start = row_start[wid], end = row_start[wid + 1];
    float erv = er[wid];
    float m = -INFINITY;
    for (int slot = start + lane; slot < end; slot += 64) {
        int s = csr_src[slot];
        float e = el[s] + erv;
        e = (e > 0.f) ? e : 0.2f * e;
        m = fmaxf(m, e);
    }
#pragma unroll
    for (int off = 1; off < 64; off <<= 1) m = fmaxf(m, __shfl_xor(m, off));
    float d = 0.f;
    for (int slot = start + lane; slot < end; slot += 64) {
        int s = csr_src[slot];
        float e = el[s] + erv;
        e = (e > 0.f) ? e : 0.2f * e;
        float w = __expf(e - m);
        d += w;
        alpha[slot] = w;
    }
#pragma unroll
    for (int off = 1; off < 64; off <<= 1) d += __shfl_xor(d, off);
    if (lane == 0) rden[wid] = (d > 0.f) ? 1.f / d : 0.f;
}

// ---------------- Gather-accumulate, layer 1 (bf16 feat) ----------------
// wave per node; 4 edge-subgroups x 16 dim-lanes; dim-lane owns 8 dims (one uint4 of bf16).
// Unroll-by-4 -> up to 16 edge rows (4KB) in flight per wave.

__global__ __launch_bounds__(256) void k_gather1(const int* __restrict__ row_start,
                                                 const int* __restrict__ csr_src,
                                                 const unsigned short* __restrict__ feat,
                                                 const float* __restrict__ alpha,
                                                 const float* __restrict__ rden,
                                                 const float* __restrict__ bias,
                                                 float* __restrict__ xout, int n) {
    int wid = (blockIdx.x * blockDim.x + threadIdx.x) >> 6;
    int lane = threadIdx.x & 63;
    if (wid >= n) return;
    int g = lane >> 4;    // edge subgroup 0..3
    int dl = lane & 15;   // dims 8*dl .. 8*dl+7
    int h = dl >> 2;      // head
    int start = row_start[wid], end = row_start[wid + 1];
    float A[8] = {};
    int slot = start + g;
    for (; slot + 12 < end; slot += 16) {
        int s0 = csr_src[slot];
        int s1 = csr_src[slot + 4];
        int s2 = csr_src[slot + 8];
        int s3 = csr_src[slot + 12];
        float w0 = alpha[(size_t)slot * 4 + h];
        float w1 = alpha[(size_t)(slot + 4) * 4 + h];
        float w2 = alpha[(size_t)(slot + 8) * 4 + h];
        float w3 = alpha[(size_t)(slot + 12) * 4 + h];
        uint4 f0 = *(const uint4*)(feat + (size_t)s0 * 128 + 8 * dl);
        uint4 f1 = *(const uint4*)(feat + (size_t)s1 * 128 + 8 * dl);
        uint4 f2 = *(const uint4*)(feat + (size_t)s2 * 128 + 8 * dl);
        uint4 f3 = *(const uint4*)(feat + (size_t)s3 * 128 + 8 * dl);
        bf2_fma(f0.x, w0, A[0], A[1]); bf2_fma(f0.y, w0, A[2], A[3]);
        bf2_fma(f0.z, w0, A[4], A[5]); bf2_fma(f0.w, w0, A[6], A[7]);
        bf2_fma(f1.x, w1, A[0], A[1]); bf2_fma(f1.y, w1, A[2], A[3]);
        bf2_fma(f1.z, w1, A[4], A[5]); bf2_fma(f1.w, w1, A[6], A[7]);
        bf2_fma(f2.x, w2, A[0], A[1]); bf2_fma(f2.y, w2, A[2], A[3]);
        bf2_fma(f2.z, w2, A[4], A[5]); bf2_fma(f2.w, w2, A[6], A[7]);
        bf2_fma(f3.x, w3, A[0], A[1]); bf2_fma(f3.y, w3, A[2], A[3]);
        bf2_fma(f3.z, w3, A[4], A[5]); bf2_fma(f3.w, w3, A[6], A[7]);
    }
    for (; slot < end; slot += 4) {
        int s = csr_src[slot];
        float w = alpha[(size_t)slot * 4 + h];
        uint4 f = *(const uint4*)(feat + (size_t)s * 128 + 8 * dl);
        bf2_fma(f.x, w, A[0], A[1]); bf2_fma(f.y, w, A[2], A[3]);
        bf2_fma(f.z, w, A[4], A[5]); bf2_fma(f.w, w, A[6], A[7]);
    }
#pragma unroll
    for (int off = 16; off < 64; off <<= 1) {
#pragma unroll
        for (int j = 0; j < 8; ++j) A[j] += __shfl_xor(A[j], off);
    }
    if (g == 0) {
        float rd = rden[wid * 4 + h];
        const float* bp = bias + 8 * dl;
        float4 b0 = *(const float4*)bp;
        float4 b1 = *(const float4*)(bp + 4);
        float o[8];
        o[0] = A[0] * rd + b0.x; o[1] = A[1] * rd + b0.y;
        o[2] = A[2] * rd + b0.z; o[3] = A[3] * rd + b0.w;
        o[4] = A[4] * rd + b1.x; o[5] = A[5] * rd + b1.y;
        o[6] = A[6] * rd + b1.z; o[7] = A[7] * rd + b1.w;
#pragma unroll
        for (int j = 0; j < 8; ++j) o[j] = (o[j] > 0.f) ? o[j] : (__expf(o[j]) - 1.f);
        float* xp = xout + (size_t)wid * 128 + 8 * dl;
        *(float4*)xp = make_float4(o[0], o[1], o[2], o[3]);
        *(float4*)(xp + 4) = make_float4(o[4], o[5], o[6], o[7]);
    }
}

// ---------------- Gather-accumulate, layer 2 (bf16 feat, final output fp32) ----------------
// 8 edge-subgroups x 8 dim-lanes; dim-lane owns 8 dims (one uint4 of bf16). Unroll-by-2.

__global__ __launch_bounds__(256) void k_gather2(const int* __restrict__ row_start,
                                                 const int* __restrict__ csr_src,
                                                 const unsigned short* __restrict__ feat,
                                                 const float* __restrict__ alpha,
                                                 const float* __restrict__ rden,
                                                 const float* __restrict__ bias,
                                                 float* __restrict__ out, int n) {
    int wid = (blockIdx.x * blockDim.x + threadIdx.x) >> 6;
    int lane = threadIdx.x & 63;
    if (wid >= n) return;
    int g = lane >> 3;    // edge subgroup 0..7
    int dl = lane & 7;    // dims 8*dl .. 8*dl+7
    int start = row_start[wid], end = row_start[wid + 1];
    float A[8] = {};
    int slot = start + g;
    for (; slot + 8 < end; slot += 16) {
        int s0 = csr_src[slot];
        int s1 = csr_src[slot + 8];
        float w0 = alpha[slot];
        float w1 = alpha[slot + 8];
        uint4 f0 = *(const uint4*)(feat + (size_t)s0 * 64 + 8 * dl);
        uint4 f1 = *(const uint4*)(feat + (size_t)s1 * 64 + 8 * dl);
        bf2_fma(f0.x, w0, A[0], A[1]); bf2_fma(f0.y, w0, A[2], A[3]);
        bf2_fma(f0.z, w0, A[4], A[5]); bf2_fma(f0.w, w0, A[6], A[7]);
        bf2_fma(f1.x, w1, A[0], A[1]); bf2_fma(f1.y, w1, A[2], A[3]);
        bf2_fma(f1.z, w1, A[4], A[5]); bf2_fma(f1.w, w1, A[6], A[7]);
    }
    if (slot < end) {
        int s = csr_src[slot];
        float w = alpha[slot];
        uint4 f = *(const uint4*)(feat + (size_t)s * 64 + 8 * dl);
        bf2_fma(f.x, w, A[0], A[1]); bf2_fma(f.y, w, A[2], A[3]);
        bf2_fma(f.z, w, A[4], A[5]); bf2_fma(f.w, w, A[6], A[7]);
    }
#pragma unroll
    for (int off = 8; off < 64; off <<= 1) {
#pragma unroll
        for (int j = 0; j < 8; ++j) A[j] += __shfl_xor(A[j], off);
    }
    if (g == 0) {
        float rd = rden[wid];
        const float* bp = bias + 8 * dl;
        float4 b0 = *(const float4*)bp;
        float4 b1 = *(const float4*)(bp + 4);
        float4 o0, o1;
        o0.x = A[0] * rd + b0.x; o0.y = A[1] * rd + b0.y;
        o0.z = A[2] * rd + b0.z; o0.w = A[3] * rd + b0.w;
        o1.x = A[4] * rd + b1.x; o1.y = A[5] * rd + b1.y;
        o1.z = A[6] * rd + b1.z; o1.w = A[7] * rd + b1.w;
        float* op = out + (size_t)wid * 64 + 8 * dl;
        *(float4*)op = o0;
        *(float4*)(op + 4) = o1;
    }
}

// ---------------- launch ----------------

extern "C" void kernel_launch(void* const* d_in, const int* in_sizes, int n_in,
                              void* d_out, int out_size, void* d_ws, size_t ws_size,
                              hipStream_t stream) {
    const float* features = (const float*)d_in[0];
    const int* src = (const int*)d_in[1];
    const int* dst = (const int*)d_in[2];
    const float* fc1_w = (const float*)d_in[3];
    const float* attn_l1 = (const float*)d_in[4];
    const float* attn_r1 = (const float*)d_in[5];
    const float* bias1 = (const float*)d_in[6];
    const float* fc2_w = (const float*)d_in[7];
    const float* attn_l2 = (const float*)d_in[8];
    const float* attn_r2 = (const float*)d_in[9];
    const float* bias2 = (const float*)d_in[10];
    const int N = in_sizes[0] / 128;
    const int E = in_sizes[1];

    char* ws = (char*)d_ws;
    size_t off = 0;
    auto alloc = [&](size_t bytes) {
        void* p = ws + off;
        off = (off + bytes + 255) & ~(size_t)255;
        return p;
    };
    // persistent
    int* cnt = (int*)alloc((size_t)N * 4);
    int* fill = (int*)alloc((size_t)N * 4);
    int* row_start = (int*)alloc((size_t)(N + 1) * 4);
    int* partials = (int*)alloc(1024 * 4);
    int* csr_src = (int*)alloc((size_t)E * 4);
    float* x2 = (float*)alloc((size_t)N * 128 * 4);
    // layer-1 region (reused by layer 2 after k_gather1 completes)
    size_t l1_off = off;
    unsigned short* feat1 = (unsigned short*)alloc((size_t)N * 128 * 2);  // bf16, 25.6 MB
    float* el1 = (float*)alloc((size_t)N * 4 * 4);
    float* er1 = (float*)alloc((size_t)N * 4 * 4);
    float* alpha1 = (float*)alloc((size_t)E * 4 * 4);
    float* rden1 = (float*)alloc((size_t)N * 4 * 4);
    // layer-2 aliases into layer-1 region (feat1 dead after k_gather1)
    off = l1_off;
    unsigned short* feat2 = (unsigned short*)alloc((size_t)N * 64 * 2);   // bf16, 12.8 MB
    float* el2 = (float*)alloc((size_t)N * 4);
    float* er2 = (float*)alloc((size_t)N * 4);
    float* alpha2 = (float*)alloc((size_t)E * 4);
    float* rden2 = (float*)alloc((size_t)N * 4);

    hipMemsetAsync(cnt, 0, (size_t)N * 4, stream);
    hipMemsetAsync(fill, 0, (size_t)N * 4, stream);

    k_count<<<(E + 255) / 256, 256, 0, stream>>>(dst, cnt, E);
    int nb = (N + 1023) / 1024;
    k_scan_local<<<nb, 256, 0, stream>>>(cnt, row_start, partials, N);
    k_scan_partials<<<1, 256, 0, stream>>>(partials, nb);
    k_scan_add<<<(N + 255) / 256, 256, 0, stream>>>(row_start, partials, N, E);
    k_scatter<<<(E + 255) / 256, 256, 0, stream>>>(src, dst, row_start, fill, csr_src, E);

    int nwave = (N + 3) / 4;
    k_gemm1<<<(N + 63) / 64, 256, 0, stream>>>(features, fc1_w, attn_l1, attn_r1, feat1, el1, er1, N);
    k_attn_w1<<<nwave, 256, 0, stream>>>(row_start, csr_src, el1, er1, alpha1, rden1, N);
    k_gather1<<<nwave, 256, 0, stream>>>(row_start, csr_src, feat1, alpha1, rden1, bias1, x2, N);
    k_gemm2<<<(N + 63) / 64, 256, 0, stream>>>(x2, fc2_w, attn_l2, attn_r2, feat2, el2, er2, N);
    k_attn_w2<<<nwave, 256, 0, stream>>>(row_start, csr_src, el2, er2, alpha2, rden2, N);
    k_gather2<<<nwave, 256, 0, stream>>>(row_start, csr_src, feat2, alpha2, rden2, bias2, (float*)d_out, N);
}

// Round 6
// 477.049 us; speedup vs baseline: 1.4759x; 1.0045x over previous
//
#include <hip/hip_runtime.h>
#include <math.h>

// ---------------- helpers ----------------

__device__ __forceinline__ unsigned int packbf2(float a, float b) {
    unsigned int ua = __float_as_uint(a);
    ua = (ua + 0x7FFFu + ((ua >> 16) & 1u)) >> 16;
    unsigned int ub = __float_as_uint(b);
    ub = (ub + 0x7FFFu + ((ub >> 16) & 1u)) & 0xFFFF0000u;
    return ua | ub;
}

__device__ __forceinline__ void bf2_fma(unsigned int u, float w, float& a0, float& a1) {
    a0 += w * __uint_as_float(u << 16);
    a1 += w * __uint_as_float(u & 0xFFFF0000u);
}

// ---------------- Fused: edge count (odd blocks) + layer-1 GEMM (even blocks) ----------------
// count: latency-bound atomics; gemm: VALU-bound -> co-scheduled on the same CUs.

__global__ __launch_bounds__(256) void k_count_gemm1(const int* __restrict__ dst,
                                                     int* __restrict__ cnt, int e,
                                                     const float* __restrict__ X,
                                                     const float* __restrict__ W,
                                                     const float* __restrict__ attn_l,
                                                     const float* __restrict__ attn_r,
                                                     unsigned short* __restrict__ feat,
                                                     float* __restrict__ el,
                                                     float* __restrict__ er, int n) {
    __shared__ float sW[64 * 128];
    __shared__ float sX[64 * 132];
    int t = threadIdx.x;
    if (blockIdx.x & 1) {
        // ---- count: 1024 edges per block ----
        int base = (blockIdx.x >> 1) * 1024 + t;
#pragma unroll
        for (int j = 0; j < 4; ++j) {
            int i = base + j * 256;
            if (i < e) atomicAdd(&cnt[dst[i]], 1);
        }
        return;
    }
    // ---- gemm1 tile ----
    int node0 = (blockIdx.x >> 1) * 64;
    {
        const float4* Xv = (const float4*)X;
        for (int i = t; i < 64 * 32; i += 256) {
            int r = i >> 5, q = i & 31;
            int node = node0 + r;
            float4 val = make_float4(0.f, 0.f, 0.f, 0.f);
            if (node < n) val = Xv[(size_t)node * 32 + q];
            *(float4*)(sX + r * 132 + q * 4) = val;
        }
    }
    {
        const float4* Wv = (const float4*)W;   // rows 0..63
        float4* sWv = (float4*)sW;
#pragma unroll
        for (int i = 0; i < 8; ++i) sWv[t + i * 256] = Wv[t + i * 256];
    }
    __syncthreads();
    int tr = t >> 4, tc = t & 15;
    float acc[4][8] = {};
    for (int k = 0; k < 64; ++k) {
        float4 w0 = *(const float4*)(sW + k * 128 + tc * 8);
        float4 w1 = *(const float4*)(sW + k * 128 + tc * 8 + 4);
#pragma unroll
        for (int i = 0; i < 4; ++i) {
            float xk = sX[(tr + 16 * i) * 132 + k];
            acc[i][0] += xk * w0.x; acc[i][1] += xk * w0.y;
            acc[i][2] += xk * w0.z; acc[i][3] += xk * w0.w;
            acc[i][4] += xk * w1.x; acc[i][5] += xk * w1.y;
            acc[i][6] += xk * w1.z; acc[i][7] += xk * w1.w;
        }
    }
    __syncthreads();
    {
        const float4* Wv = (const float4*)(W + 64 * 128);   // rows 64..127
        float4* sWv = (float4*)sW;
#pragma unroll
        for (int i = 0; i < 8; ++i) sWv[t + i * 256] = Wv[t + i * 256];
    }
    __syncthreads();
    for (int k = 0; k < 64; ++k) {
        float4 w0 = *(const float4*)(sW + k * 128 + tc * 8);
        float4 w1 = *(const float4*)(sW + k * 128 + tc * 8 + 4);
#pragma unroll
        for (int i = 0; i < 4; ++i) {
            float xk = sX[(tr + 16 * i) * 132 + (64 + k)];
            acc[i][0] += xk * w0.x; acc[i][1] += xk * w0.y;
            acc[i][2] += xk * w0.z; acc[i][3] += xk * w0.w;
            acc[i][4] += xk * w1.x; acc[i][5] += xk * w1.y;
            acc[i][6] += xk * w1.z; acc[i][7] += xk * w1.w;
        }
    }
    int h = tc >> 2;
    int dbase = (tc & 3) * 8;
    float al[8], ar[8];
#pragma unroll
    for (int j = 0; j < 8; ++j) {
        al[j] = attn_l[h * 32 + dbase + j];
        ar[j] = attn_r[h * 32 + dbase + j];
    }
#pragma unroll
    for (int i = 0; i < 4; ++i) {
        int node = node0 + tr + 16 * i;
        float pl = 0.f, pr = 0.f;
#pragma unroll
        for (int j = 0; j < 8; ++j) { pl += acc[i][j] * al[j]; pr += acc[i][j] * ar[j]; }
        pl += __shfl_xor(pl, 1); pl += __shfl_xor(pl, 2);
        pr += __shfl_xor(pr, 1); pr += __shfl_xor(pr, 2);
        if (node < n) {
            uint4 pk;
            pk.x = packbf2(acc[i][0], acc[i][1]);
            pk.y = packbf2(acc[i][2], acc[i][3]);
            pk.z = packbf2(acc[i][4], acc[i][5]);
            pk.w = packbf2(acc[i][6], acc[i][7]);
            *(uint4*)(feat + (size_t)node * 128 + tc * 8) = pk;
            if ((tc & 3) == 0) { el[node * 4 + h] = pl; er[node * 4 + h] = pr; }
        }
    }
}

// ---------------- scans ----------------

__global__ __launch_bounds__(256) void k_scan_local(const int* __restrict__ cnt,
                                                    int* __restrict__ row_start,
                                                    int* __restrict__ partials, int n) {
    __shared__ int sdata[256];
    int tid = threadIdx.x;
    int base = blockIdx.x * 1024 + tid * 4;
    int v0 = (base + 0 < n) ? cnt[base + 0] : 0;
    int v1 = (base + 1 < n) ? cnt[base + 1] : 0;
    int v2 = (base + 2 < n) ? cnt[base + 2] : 0;
    int v3 = (base + 3 < n) ? cnt[base + 3] : 0;
    int s = v0 + v1 + v2 + v3;
    sdata[tid] = s;
    __syncthreads();
    for (int off = 1; off < 256; off <<= 1) {
        int y = (tid >= off) ? sdata[tid - off] : 0;
        __syncthreads();
        sdata[tid] += y;
        __syncthreads();
    }
    int run = sdata[tid] - s;
    if (base + 0 < n) row_start[base + 0] = run;
    run += v0;
    if (base + 1 < n) row_start[base + 1] = run;
    run += v1;
    if (base + 2 < n) row_start[base + 2] = run;
    run += v2;
    if (base + 3 < n) row_start[base + 3] = run;
    if (tid == 255) partials[blockIdx.x] = sdata[255];
}

__global__ __launch_bounds__(256) void k_scan_partials(int* partials, int nb) {
    __shared__ int sdata[256];
    int tid = threadIdx.x;
    int v = (tid < nb) ? partials[tid] : 0;
    sdata[tid] = v;
    __syncthreads();
    for (int off = 1; off < 256; off <<= 1) {
        int y = (tid >= off) ? sdata[tid - off] : 0;
        __syncthreads();
        sdata[tid] += y;
        __syncthreads();
    }
    if (tid < nb) partials[tid] = sdata[tid] - v;
}

// writes final row_start AND initializes fill = row_start (scatter uses fill directly)
__global__ __launch_bounds__(256) void k_scan_add(int* __restrict__ row_start,
                                                  int* __restrict__ fill,
                                                  const int* __restrict__ partials,
                                                  int n, int total) {
    int i = blockIdx.x * 256 + threadIdx.x;
    if (i < n) {
        int v = row_start[i] + partials[i >> 10];
        row_start[i] = v;
        fill[i] = v;
    }
    if (i == 0) row_start[n] = total;
}

// ---------------- scatter: 2 edges/thread, direct ticket on fill ----------------

__global__ __launch_bounds__(256) void k_scatter(const int* __restrict__ src,
                                                 const int* __restrict__ dst,
                                                 int* __restrict__ fill,
                                                 int* __restrict__ csr_src, int e) {
    int i = blockIdx.x * 512 + threadIdx.x;
    int j = i + 256;
    if (i < e) {
        int d = dst[i];
        int pos = atomicAdd(&fill[d], 1);
        csr_src[pos] = src[i];
    }
    if (j < e) {
        int d = dst[j];
        int pos = atomicAdd(&fill[d], 1);
        csr_src[pos] = src[j];
    }
}

// ---------------- Layer 2 GEMM: [N,128] @ [128,64] + fused el/er (H=1), bf16 feat out ----------------

__global__ __launch_bounds__(256) void k_gemm2(const float* __restrict__ X,
                                               const float* __restrict__ W,
                                               const float* __restrict__ attn_l,
                                               const float* __restrict__ attn_r,
                                               unsigned short* __restrict__ feat,
                                               float* __restrict__ el,
                                               float* __restrict__ er, int n) {
    __shared__ float sW[128 * 64];
    __shared__ float sX[64 * 132];
    int t = threadIdx.x;
    {
        const float4* Wv = (const float4*)W;
        float4* sWv = (float4*)sW;
#pragma unroll
        for (int i = 0; i < 8; ++i) sWv[t + i * 256] = Wv[t + i * 256];
    }
    int node0 = blockIdx.x * 64;
    {
        const float4* Xv = (const float4*)X;
        for (int i = t; i < 64 * 32; i += 256) {
            int r = i >> 5, q = i & 31;
            int node = node0 + r;
            float4 val = make_float4(0.f, 0.f, 0.f, 0.f);
            if (node < n) val = Xv[(size_t)node * 32 + q];
            *(float4*)(sX + r * 132 + q * 4) = val;
        }
    }
    __syncthreads();
    int tr = t >> 3, tc = t & 7;
    float acc[2][8] = {};
    for (int k = 0; k < 128; ++k) {
        float4 w0 = *(const float4*)(sW + k * 64 + tc * 8);
        float4 w1 = *(const float4*)(sW + k * 64 + tc * 8 + 4);
#pragma unroll
        for (int i = 0; i < 2; ++i) {
            float xk = sX[(tr + 32 * i) * 132 + k];
            acc[i][0] += xk * w0.x; acc[i][1] += xk * w0.y;
            acc[i][2] += xk * w0.z; acc[i][3] += xk * w0.w;
            acc[i][4] += xk * w1.x; acc[i][5] += xk * w1.y;
            acc[i][6] += xk * w1.z; acc[i][7] += xk * w1.w;
        }
    }
    float al[8], ar[8];
#pragma unroll
    for (int j = 0; j < 8; ++j) { al[j] = attn_l[tc * 8 + j]; ar[j] = attn_r[tc * 8 + j]; }
#pragma unroll
    for (int i = 0; i < 2; ++i) {
        int node = node0 + tr + 32 * i;
        float pl = 0.f, pr = 0.f;
#pragma unroll
        for (int j = 0; j < 8; ++j) { pl += acc[i][j] * al[j]; pr += acc[i][j] * ar[j]; }
        pl += __shfl_xor(pl, 1); pl += __shfl_xor(pl, 2); pl += __shfl_xor(pl, 4);
        pr += __shfl_xor(pr, 1); pr += __shfl_xor(pr, 2); pr += __shfl_xor(pr, 4);
        if (node < n) {
            uint4 pk;
            pk.x = packbf2(acc[i][0], acc[i][1]);
            pk.y = packbf2(acc[i][2], acc[i][3]);
            pk.z = packbf2(acc[i][4], acc[i][5]);
            pk.w = packbf2(acc[i][6], acc[i][7]);
            *(uint4*)(feat + (size_t)node * 64 + tc * 8) = pk;
            if (tc == 0) { el[node] = pl; er[node] = pr; }
        }
    }
}

// ---------------- Attention weights, layer 1 (H=4) ----------------

__global__ __launch_bounds__(256) void k_attn_w1(const int* __restrict__ row_start,
                                                 const int* __restrict__ csr_src,
                                                 const float* __restrict__ el,
                                                 const float* __restrict__ er,
                                                 float* __restrict__ alpha,
                                                 float* __restrict__ rden, int n) {
    int wid = (blockIdx.x * blockDim.x + threadIdx.x) >> 6;
    int lane = threadIdx.x & 63;
    if (wid >= n) return;
    int start = row_start[wid], end = row_start[wid + 1];
    float4 er4 = *(const float4*)(er + wid * 4);
    float m0 = -INFINITY, m1 = -INFINITY, m2 = -INFINITY, m3 = -INFINITY;
    for (int slot = start + lane; slot < end; slot += 64) {
        int s = csr_src[slot];
        float4 e4 = *(const float4*)(el + s * 4);
        float e0 = e4.x + er4.x, e1 = e4.y + er4.y, e2 = e4.z + er4.z, e3 = e4.w + er4.w;
        e0 = (e0 > 0.f) ? e0 : 0.2f * e0;
        e1 = (e1 > 0.f) ? e1 : 0.2f * e1;
        e2 = (e2 > 0.f) ? e2 : 0.2f * e2;
        e3 = (e3 > 0.f) ? e3 : 0.2f * e3;
        m0 = fmaxf(m0, e0); m1 = fmaxf(m1, e1); m2 = fmaxf(m2, e2); m3 = fmaxf(m3, e3);
    }
#pragma unroll
    for (int off = 1; off < 64; off <<= 1) {
        m0 = fmaxf(m0, __shfl_xor(m0, off));
        m1 = fmaxf(m1, __shfl_xor(m1, off));
        m2 = fmaxf(m2, __shfl_xor(m2, off));
        m3 = fmaxf(m3, __shfl_xor(m3, off));
    }
    float d0 = 0.f, d1 = 0.f, d2 = 0.f, d3 = 0.f;
    for (int slot = start + lane; slot < end; slot += 64) {
        int s = csr_src[slot];
        float4 e4 = *(const float4*)(el + s * 4);
        float e0 = e4.x + er4.x, e1 = e4.y + er4.y, e2 = e4.z + er4.z, e3 = e4.w + er4.w;
        e0 = (e0 > 0.f) ? e0 : 0.2f * e0;
        e1 = (e1 > 0.f) ? e1 : 0.2f * e1;
        e2 = (e2 > 0.f) ? e2 : 0.2f * e2;
        e3 = (e3 > 0.f) ? e3 : 0.2f * e3;
        float w0 = __expf(e0 - m0), w1 = __expf(e1 - m1);
        float w2 = __expf(e2 - m2), w3 = __expf(e3 - m3);
        d0 += w0; d1 += w1; d2 += w2; d3 += w3;
        *(float4*)(alpha + (size_t)slot * 4) = make_float4(w0, w1, w2, w3);
    }
#pragma unroll
    for (int off = 1; off < 64; off <<= 1) {
        d0 += __shfl_xor(d0, off);
        d1 += __shfl_xor(d1, off);
        d2 += __shfl_xor(d2, off);
        d3 += __shfl_xor(d3, off);
    }
    if (lane == 0) {
        float4 rd;
        rd.x = (d0 > 0.f) ? 1.f / d0 : 0.f;
        rd.y = (d1 > 0.f) ? 1.f / d1 : 0.f;
        rd.z = (d2 > 0.f) ? 1.f / d2 : 0.f;
        rd.w = (d3 > 0.f) ? 1.f / d3 : 0.f;
        *(float4*)(rden + wid * 4) = rd;
    }
}

// ---------------- Attention weights, layer 2 (H=1) ----------------

__global__ __launch_bounds__(256) void k_attn_w2(const int* __restrict__ row_start,
                                                 const int* __restrict__ csr_src,
                                                 const float* __restrict__ el,
                                                 const float* __restrict__ er,
                                                 float* __restrict__ alpha,
                                                 float* __restrict__ rden, int n) {
    int wid = (blockIdx.x * blockDim.x + threadIdx.x) >> 6;
    int lane = threadIdx.x & 63;
    if (wid >= n) return;
    int start = row_start[wid], end = row_start[wid + 1];
    float erv = er[wid];
    float m = -INFINITY;
    for (int slot = start + lane; slot < end; slot += 64) {
        int s = csr_src[slot];
        float e = el[s] + erv;
        e = (e > 0.f) ? e : 0.2f * e;
        m = fmaxf(m, e);
    }
#pragma unroll
    for (int off = 1; off < 64; off <<= 1) m = fmaxf(m, __shfl_xor(m, off));
    float d = 0.f;
    for (int slot = start + lane; slot < end; slot += 64) {
        int s = csr_src[slot];
        float e = el[s] + erv;
        e = (e > 0.f) ? e : 0.2f * e;
        float w = __expf(e - m);
        d += w;
        alpha[slot] = w;
    }
#pragma unroll
    for (int off = 1; off < 64; off <<= 1) d += __shfl_xor(d, off);
    if (lane == 0) rden[wid] = (d > 0.f) ? 1.f / d : 0.f;
}

// ---------------- Gather-accumulate, layer 1 (bf16 feat) ----------------

__global__ __launch_bounds__(256) void k_gather1(const int* __restrict__ row_start,
                                                 const int* __restrict__ csr_src,
                                                 const unsigned short* __restrict__ feat,
                                                 const float* __restrict__ alpha,
                                                 const float* __restrict__ rden,
                                                 const float* __restrict__ bias,
                                                 float* __restrict__ xout, int n) {
    int wid = (blockIdx.x * blockDim.x + threadIdx.x) >> 6;
    int lane = threadIdx.x & 63;
    if (wid >= n) return;
    int g = lane >> 4;    // edge subgroup 0..3
    int dl = lane & 15;   // dims 8*dl .. 8*dl+7
    int h = dl >> 2;      // head
    int start = row_start[wid], end = row_start[wid + 1];
    float A[8] = {};
    int slot = start + g;
    for (; slot + 12 < end; slot += 16) {
        int s0 = csr_src[slot];
        int s1 = csr_src[slot + 4];
        int s2 = csr_src[slot + 8];
        int s3 = csr_src[slot + 12];
        float w0 = alpha[(size_t)slot * 4 + h];
        float w1 = alpha[(size_t)(slot + 4) * 4 + h];
        float w2 = alpha[(size_t)(slot + 8) * 4 + h];
        float w3 = alpha[(size_t)(slot + 12) * 4 + h];
        uint4 f0 = *(const uint4*)(feat + (size_t)s0 * 128 + 8 * dl);
        uint4 f1 = *(const uint4*)(feat + (size_t)s1 * 128 + 8 * dl);
        uint4 f2 = *(const uint4*)(feat + (size_t)s2 * 128 + 8 * dl);
        uint4 f3 = *(const uint4*)(feat + (size_t)s3 * 128 + 8 * dl);
        bf2_fma(f0.x, w0, A[0], A[1]); bf2_fma(f0.y, w0, A[2], A[3]);
        bf2_fma(f0.z, w0, A[4], A[5]); bf2_fma(f0.w, w0, A[6], A[7]);
        bf2_fma(f1.x, w1, A[0], A[1]); bf2_fma(f1.y, w1, A[2], A[3]);
        bf2_fma(f1.z, w1, A[4], A[5]); bf2_fma(f1.w, w1, A[6], A[7]);
        bf2_fma(f2.x, w2, A[0], A[1]); bf2_fma(f2.y, w2, A[2], A[3]);
        bf2_fma(f2.z, w2, A[4], A[5]); bf2_fma(f2.w, w2, A[6], A[7]);
        bf2_fma(f3.x, w3, A[0], A[1]); bf2_fma(f3.y, w3, A[2], A[3]);
        bf2_fma(f3.z, w3, A[4], A[5]); bf2_fma(f3.w, w3, A[6], A[7]);
    }
    for (; slot < end; slot += 4) {
        int s = csr_src[slot];
        float w = alpha[(size_t)slot * 4 + h];
        uint4 f = *(const uint4*)(feat + (size_t)s * 128 + 8 * dl);
        bf2_fma(f.x, w, A[0], A[1]); bf2_fma(f.y, w, A[2], A[3]);
        bf2_fma(f.z, w, A[4], A[5]); bf2_fma(f.w, w, A[6], A[7]);
    }
#pragma unroll
    for (int off = 16; off < 64; off <<= 1) {
#pragma unroll
        for (int j = 0; j < 8; ++j) A[j] += __shfl_xor(A[j], off);
    }
    if (g == 0) {
        float rd = rden[wid * 4 + h];
        const float* bp = bias + 8 * dl;
        float4 b0 = *(const float4*)bp;
        float4 b1 = *(const float4*)(bp + 4);
        float o[8];
        o[0] = A[0] * rd + b0.x; o[1] = A[1] * rd + b0.y;
        o[2] = A[2] * rd + b0.z; o[3] = A[3] * rd + b0.w;
        o[4] = A[4] * rd + b1.x; o[5] = A[5] * rd + b1.y;
        o[6] = A[6] * rd + b1.z; o[7] = A[7] * rd + b1.w;
#pragma unroll
        for (int j = 0; j < 8; ++j) o[j] = (o[j] > 0.f) ? o[j] : (__expf(o[j]) - 1.f);
        float* xp = xout + (size_t)wid * 128 + 8 * dl;
        *(float4*)xp = make_float4(o[0], o[1], o[2], o[3]);
        *(float4*)(xp + 4) = make_float4(o[4], o[5], o[6], o[7]);
    }
}

// ---------------- Gather-accumulate, layer 2 (bf16 feat, final output fp32) ----------------

__global__ __launch_bounds__(256) void k_gather2(const int* __restrict__ row_start,
                                                 const int* __restrict__ csr_src,
                                                 const unsigned short* __restrict__ feat,
                                                 const float* __restrict__ alpha,
                                                 const float* __restrict__ rden,
                                                 const float* __restrict__ bias,
                                                 float* __restrict__ out, int n) {
    int wid = (blockIdx.x * blockDim.x + threadIdx.x) >> 6;
    int lane = threadIdx.x & 63;
    if (wid >= n) return;
    int g = lane >> 3;    // edge subgroup 0..7
    int dl = lane & 7;    // dims 8*dl .. 8*dl+7
    int start = row_start[wid], end = row_start[wid + 1];
    float A[8] = {};
    int slot = start + g;
    for (; slot + 8 < end; slot += 16) {
        int s0 = csr_src[slot];
        int s1 = csr_src[slot + 8];
        float w0 = alpha[slot];
        float w1 = alpha[slot + 8];
        uint4 f0 = *(const uint4*)(feat + (size_t)s0 * 64 + 8 * dl);
        uint4 f1 = *(const uint4*)(feat + (size_t)s1 * 64 + 8 * dl);
        bf2_fma(f0.x, w0, A[0], A[1]); bf2_fma(f0.y, w0, A[2], A[3]);
        bf2_fma(f0.z, w0, A[4], A[5]); bf2_fma(f0.w, w0, A[6], A[7]);
        bf2_fma(f1.x, w1, A[0], A[1]); bf2_fma(f1.y, w1, A[2], A[3]);
        bf2_fma(f1.z, w1, A[4], A[5]); bf2_fma(f1.w, w1, A[6], A[7]);
    }
    if (slot < end) {
        int s = csr_src[slot];
        float w = alpha[slot];
        uint4 f = *(const uint4*)(feat + (size_t)s * 64 + 8 * dl);
        bf2_fma(f.x, w, A[0], A[1]); bf2_fma(f.y, w, A[2], A[3]);
        bf2_fma(f.z, w, A[4], A[5]); bf2_fma(f.w, w, A[6], A[7]);
    }
#pragma unroll
    for (int off = 8; off < 64; off <<= 1) {
#pragma unroll
        for (int j = 0; j < 8; ++j) A[j] += __shfl_xor(A[j], off);
    }
    if (g == 0) {
        float rd = rden[wid];
        const float* bp = bias + 8 * dl;
        float4 b0 = *(const float4*)bp;
        float4 b1 = *(const float4*)(bp + 4);
        float4 o0, o1;
        o0.x = A[0] * rd + b0.x; o0.y = A[1] * rd + b0.y;
        o0.z = A[2] * rd + b0.z; o0.w = A[3] * rd + b0.w;
        o1.x = A[4] * rd + b1.x; o1.y = A[5] * rd + b1.y;
        o1.z = A[6] * rd + b1.z; o1.w = A[7] * rd + b1.w;
        float* op = out + (size_t)wid * 64 + 8 * dl;
        *(float4*)op = o0;
        *(float4*)(op + 4) = o1;
    }
}

// ---------------- launch ----------------

extern "C" void kernel_launch(void* const* d_in, const int* in_sizes, int n_in,
                              void* d_out, int out_size, void* d_ws, size_t ws_size,
                              hipStream_t stream) {
    const float* features = (const float*)d_in[0];
    const int* src = (const int*)d_in[1];
    const int* dst = (const int*)d_in[2];
    const float* fc1_w = (const float*)d_in[3];
    const float* attn_l1 = (const float*)d_in[4];
    const float* attn_r1 = (const float*)d_in[5];
    const float* bias1 = (const float*)d_in[6];
    const float* fc2_w = (const float*)d_in[7];
    const float* attn_l2 = (const float*)d_in[8];
    const float* attn_r2 = (const float*)d_in[9];
    const float* bias2 = (const float*)d_in[10];
    const int N = in_sizes[0] / 128;
    const int E = in_sizes[1];

    char* ws = (char*)d_ws;
    size_t off = 0;
    auto alloc = [&](size_t bytes) {
        void* p = ws + off;
        off = (off + bytes + 255) & ~(size_t)255;
        return p;
    };
    // persistent
    int* cnt = (int*)alloc((size_t)N * 4);
    int* fill = (int*)alloc((size_t)N * 4);
    int* row_start = (int*)alloc((size_t)(N + 1) * 4);
    int* partials = (int*)alloc(1024 * 4);
    int* csr_src = (int*)alloc((size_t)E * 4);
    float* x2 = (float*)alloc((size_t)N * 128 * 4);
    // layer-1 region (reused by layer 2 after k_gather1 completes)
    size_t l1_off = off;
    unsigned short* feat1 = (unsigned short*)alloc((size_t)N * 128 * 2);  // bf16
    float* el1 = (float*)alloc((size_t)N * 4 * 4);
    float* er1 = (float*)alloc((size_t)N * 4 * 4);
    float* alpha1 = (float*)alloc((size_t)E * 4 * 4);
    float* rden1 = (float*)alloc((size_t)N * 4 * 4);
    // layer-2 aliases into layer-1 region (feat1 dead after k_gather1)
    off = l1_off;
    unsigned short* feat2 = (unsigned short*)alloc((size_t)N * 64 * 2);   // bf16
    float* el2 = (float*)alloc((size_t)N * 4);
    float* er2 = (float*)alloc((size_t)N * 4);
    float* alpha2 = (float*)alloc((size_t)E * 4);
    float* rden2 = (float*)alloc((size_t)N * 4);

    hipMemsetAsync(cnt, 0, (size_t)N * 4, stream);

    // fused count + gemm1: even blocks gemm tile, odd blocks count 1024 edges
    int ngemm = (N + 63) / 64;                 // 1563
    int ncount = (E + 1023) / 1024;            // 1563
    int nfused = 2 * ((ngemm > ncount) ? ngemm : ncount);
    k_count_gemm1<<<nfused, 256, 0, stream>>>(dst, cnt, E,
                                              features, fc1_w, attn_l1, attn_r1,
                                              feat1, el1, er1, N);
    int nb = (N + 1023) / 1024;
    k_scan_local<<<nb, 256, 0, stream>>>(cnt, row_start, partials, N);
    k_scan_partials<<<1, 256, 0, stream>>>(partials, nb);
    k_scan_add<<<(N + 255) / 256, 256, 0, stream>>>(row_start, fill, partials, N, E);
    k_scatter<<<(E + 511) / 512, 256, 0, stream>>>(src, dst, fill, csr_src, E);

    int nwave = (N + 3) / 4;
    k_attn_w1<<<nwave, 256, 0, stream>>>(row_start, csr_src, el1, er1, alpha1, rden1, N);
    k_gather1<<<nwave, 256, 0, stream>>>(row_start, csr_src, feat1, alpha1, rden1, bias1, x2, N);
    k_gemm2<<<(N + 63) / 64, 256, 0, stream>>>(x2, fc2_w, attn_l2, attn_r2, feat2, el2, er2, N);
    k_attn_w2<<<nwave, 256, 0, stream>>>(row_start, csr_src, el2, er2, alpha2, rden2, N);
    k_gather2<<<nwave, 256, 0, stream>>>(row_start, csr_src, feat2, alpha2, rden2, bias2, (float*)d_out, N);
}

// Round 7
// 424.520 us; speedup vs baseline: 1.6586x; 1.1237x over previous
//
#include <hip/hip_runtime.h>
#include <math.h>

// ---------------- helpers ----------------

__device__ __forceinline__ unsigned int packbf2(float a, float b) {
    unsigned int ua = __float_as_uint(a);
    ua = (ua + 0x7FFFu + ((ua >> 16) & 1u)) >> 16;
    unsigned int ub = __float_as_uint(b);
    ub = (ub + 0x7FFFu + ((ub >> 16) & 1u)) & 0xFFFF0000u;
    return ua | ub;
}

__device__ __forceinline__ void bf2_fma(unsigned int u, float w, float& a0, float& a1) {
    a0 += w * __uint_as_float(u << 16);
    a1 += w * __uint_as_float(u & 0xFFFF0000u);
}

// ---------------- Layer-1 GEMM with embedded edge count ----------------
// Every block: (a) counts a 1024-edge slice via fire-and-forget atomics issued
// right after the first barrier (latency hides under the FMA loop, no occupancy
// cost), (b) computes a 64-node GEMM tile with fused el/er and bf16 feat out.

__global__ __launch_bounds__(256) void k_gemm1_count(const int* __restrict__ dst,
                                                     int* __restrict__ cnt, int e,
                                                     const float* __restrict__ X,
                                                     const float* __restrict__ W,
                                                     const float* __restrict__ attn_l,
                                                     const float* __restrict__ attn_r,
                                                     unsigned short* __restrict__ feat,
                                                     float* __restrict__ el,
                                                     float* __restrict__ er, int n) {
    __shared__ float sW[64 * 128];
    __shared__ float sX[64 * 132];
    int t = threadIdx.x;
    // count slice: load dst values early (coalesced)
    int ebase = blockIdx.x * 1024 + t;
    int d0 = (ebase < e) ? dst[ebase] : -1;
    int d1 = (ebase + 256 < e) ? dst[ebase + 256] : -1;
    int d2 = (ebase + 512 < e) ? dst[ebase + 512] : -1;
    int d3 = (ebase + 768 < e) ? dst[ebase + 768] : -1;

    int node0 = blockIdx.x * 64;
    {
        const float4* Xv = (const float4*)X;
        for (int i = t; i < 64 * 32; i += 256) {
            int r = i >> 5, q = i & 31;
            int node = node0 + r;
            float4 val = make_float4(0.f, 0.f, 0.f, 0.f);
            if (node < n) val = Xv[(size_t)node * 32 + q];
            *(float4*)(sX + r * 132 + q * 4) = val;
        }
    }
    {
        const float4* Wv = (const float4*)W;   // rows 0..63
        float4* sWv = (float4*)sW;
#pragma unroll
        for (int i = 0; i < 8; ++i) sWv[t + i * 256] = Wv[t + i * 256];
    }
    __syncthreads();
    // fire-and-forget count atomics: no return use -> no dependent wait;
    // latency hides under the 64-iteration FMA loop below.
    if (d0 >= 0) atomicAdd(&cnt[d0], 1);
    if (d1 >= 0) atomicAdd(&cnt[d1], 1);
    if (d2 >= 0) atomicAdd(&cnt[d2], 1);
    if (d3 >= 0) atomicAdd(&cnt[d3], 1);

    int tr = t >> 4, tc = t & 15;
    float acc[4][8] = {};
    for (int k = 0; k < 64; ++k) {
        float4 w0 = *(const float4*)(sW + k * 128 + tc * 8);
        float4 w1 = *(const float4*)(sW + k * 128 + tc * 8 + 4);
#pragma unroll
        for (int i = 0; i < 4; ++i) {
            float xk = sX[(tr + 16 * i) * 132 + k];
            acc[i][0] += xk * w0.x; acc[i][1] += xk * w0.y;
            acc[i][2] += xk * w0.z; acc[i][3] += xk * w0.w;
            acc[i][4] += xk * w1.x; acc[i][5] += xk * w1.y;
            acc[i][6] += xk * w1.z; acc[i][7] += xk * w1.w;
        }
    }
    __syncthreads();
    {
        const float4* Wv = (const float4*)(W + 64 * 128);   // rows 64..127
        float4* sWv = (float4*)sW;
#pragma unroll
        for (int i = 0; i < 8; ++i) sWv[t + i * 256] = Wv[t + i * 256];
    }
    __syncthreads();
    for (int k = 0; k < 64; ++k) {
        float4 w0 = *(const float4*)(sW + k * 128 + tc * 8);
        float4 w1 = *(const float4*)(sW + k * 128 + tc * 8 + 4);
#pragma unroll
        for (int i = 0; i < 4; ++i) {
            float xk = sX[(tr + 16 * i) * 132 + (64 + k)];
            acc[i][0] += xk * w0.x; acc[i][1] += xk * w0.y;
            acc[i][2] += xk * w0.z; acc[i][3] += xk * w0.w;
            acc[i][4] += xk * w1.x; acc[i][5] += xk * w1.y;
            acc[i][6] += xk * w1.z; acc[i][7] += xk * w1.w;
        }
    }
    int h = tc >> 2;
    int dbase = (tc & 3) * 8;
    float al[8], ar[8];
#pragma unroll
    for (int j = 0; j < 8; ++j) {
        al[j] = attn_l[h * 32 + dbase + j];
        ar[j] = attn_r[h * 32 + dbase + j];
    }
#pragma unroll
    for (int i = 0; i < 4; ++i) {
        int node = node0 + tr + 16 * i;
        float pl = 0.f, pr = 0.f;
#pragma unroll
        for (int j = 0; j < 8; ++j) { pl += acc[i][j] * al[j]; pr += acc[i][j] * ar[j]; }
        pl += __shfl_xor(pl, 1); pl += __shfl_xor(pl, 2);
        pr += __shfl_xor(pr, 1); pr += __shfl_xor(pr, 2);
        if (node < n) {
            uint4 pk;
            pk.x = packbf2(acc[i][0], acc[i][1]);
            pk.y = packbf2(acc[i][2], acc[i][3]);
            pk.z = packbf2(acc[i][4], acc[i][5]);
            pk.w = packbf2(acc[i][6], acc[i][7]);
            *(uint4*)(feat + (size_t)node * 128 + tc * 8) = pk;
            if ((tc & 3) == 0) { el[node * 4 + h] = pl; er[node * 4 + h] = pr; }
        }
    }
}

// ---------------- scans ----------------

__global__ __launch_bounds__(256) void k_scan_local(const int* __restrict__ cnt,
                                                    int* __restrict__ row_start,
                                                    int* __restrict__ partials, int n) {
    __shared__ int sdata[256];
    int tid = threadIdx.x;
    int base = blockIdx.x * 1024 + tid * 4;
    int v0 = (base + 0 < n) ? cnt[base + 0] : 0;
    int v1 = (base + 1 < n) ? cnt[base + 1] : 0;
    int v2 = (base + 2 < n) ? cnt[base + 2] : 0;
    int v3 = (base + 3 < n) ? cnt[base + 3] : 0;
    int s = v0 + v1 + v2 + v3;
    sdata[tid] = s;
    __syncthreads();
    for (int off = 1; off < 256; off <<= 1) {
        int y = (tid >= off) ? sdata[tid - off] : 0;
        __syncthreads();
        sdata[tid] += y;
        __syncthreads();
    }
    int run = sdata[tid] - s;
    if (base + 0 < n) row_start[base + 0] = run;
    run += v0;
    if (base + 1 < n) row_start[base + 1] = run;
    run += v1;
    if (base + 2 < n) row_start[base + 2] = run;
    run += v2;
    if (base + 3 < n) row_start[base + 3] = run;
    if (tid == 255) partials[blockIdx.x] = sdata[255];
}

__global__ __launch_bounds__(256) void k_scan_partials(int* partials, int nb) {
    __shared__ int sdata[256];
    int tid = threadIdx.x;
    int v = (tid < nb) ? partials[tid] : 0;
    sdata[tid] = v;
    __syncthreads();
    for (int off = 1; off < 256; off <<= 1) {
        int y = (tid >= off) ? sdata[tid - off] : 0;
        __syncthreads();
        sdata[tid] += y;
        __syncthreads();
    }
    if (tid < nb) partials[tid] = sdata[tid] - v;
}

// writes final row_start AND initializes fill = row_start (scatter tickets on fill)
__global__ __launch_bounds__(256) void k_scan_add(int* __restrict__ row_start,
                                                  int* __restrict__ fill,
                                                  const int* __restrict__ partials,
                                                  int n, int total) {
    int i = blockIdx.x * 256 + threadIdx.x;
    if (i < n) {
        int v = row_start[i] + partials[i >> 10];
        row_start[i] = v;
        fill[i] = v;
    }
    if (i == 0) row_start[n] = total;
}

// ---------------- scatter: 4 edges/thread, batched issue for 4-deep MLP ----------------

__global__ __launch_bounds__(256) void k_scatter(const int* __restrict__ src,
                                                 const int* __restrict__ dst,
                                                 int* __restrict__ fill,
                                                 int* __restrict__ csr_src, int e) {
    int base = blockIdx.x * 1024 + threadIdx.x;
    int i0 = base, i1 = base + 256, i2 = base + 512, i3 = base + 768;
    int d0 = (i0 < e) ? dst[i0] : -1;
    int d1 = (i1 < e) ? dst[i1] : -1;
    int d2 = (i2 < e) ? dst[i2] : -1;
    int d3 = (i3 < e) ? dst[i3] : -1;
    int s0 = (i0 < e) ? src[i0] : 0;
    int s1 = (i1 < e) ? src[i1] : 0;
    int s2 = (i2 < e) ? src[i2] : 0;
    int s3 = (i3 < e) ? src[i3] : 0;
    int p0 = 0, p1 = 0, p2 = 0, p3 = 0;
    if (d0 >= 0) p0 = atomicAdd(&fill[d0], 1);
    if (d1 >= 0) p1 = atomicAdd(&fill[d1], 1);
    if (d2 >= 0) p2 = atomicAdd(&fill[d2], 1);
    if (d3 >= 0) p3 = atomicAdd(&fill[d3], 1);
    if (d0 >= 0) csr_src[p0] = s0;
    if (d1 >= 0) csr_src[p1] = s1;
    if (d2 >= 0) csr_src[p2] = s2;
    if (d3 >= 0) csr_src[p3] = s3;
}

// ---------------- Layer 2 GEMM: [N,128] @ [128,64] + fused el/er (H=1), bf16 feat out ----------------

__global__ __launch_bounds__(256) void k_gemm2(const float* __restrict__ X,
                                               const float* __restrict__ W,
                                               const float* __restrict__ attn_l,
                                               const float* __restrict__ attn_r,
                                               unsigned short* __restrict__ feat,
                                               float* __restrict__ el,
                                               float* __restrict__ er, int n) {
    __shared__ float sW[128 * 64];
    __shared__ float sX[64 * 132];
    int t = threadIdx.x;
    {
        const float4* Wv = (const float4*)W;
        float4* sWv = (float4*)sW;
#pragma unroll
        for (int i = 0; i < 8; ++i) sWv[t + i * 256] = Wv[t + i * 256];
    }
    int node0 = blockIdx.x * 64;
    {
        const float4* Xv = (const float4*)X;
        for (int i = t; i < 64 * 32; i += 256) {
            int r = i >> 5, q = i & 31;
            int node = node0 + r;
            float4 val = make_float4(0.f, 0.f, 0.f, 0.f);
            if (node < n) val = Xv[(size_t)node * 32 + q];
            *(float4*)(sX + r * 132 + q * 4) = val;
        }
    }
    __syncthreads();
    int tr = t >> 3, tc = t & 7;
    float acc[2][8] = {};
    for (int k = 0; k < 128; ++k) {
        float4 w0 = *(const float4*)(sW + k * 64 + tc * 8);
        float4 w1 = *(const float4*)(sW + k * 64 + tc * 8 + 4);
#pragma unroll
        for (int i = 0; i < 2; ++i) {
            float xk = sX[(tr + 32 * i) * 132 + k];
            acc[i][0] += xk * w0.x; acc[i][1] += xk * w0.y;
            acc[i][2] += xk * w0.z; acc[i][3] += xk * w0.w;
            acc[i][4] += xk * w1.x; acc[i][5] += xk * w1.y;
            acc[i][6] += xk * w1.z; acc[i][7] += xk * w1.w;
        }
    }
    float al[8], ar[8];
#pragma unroll
    for (int j = 0; j < 8; ++j) { al[j] = attn_l[tc * 8 + j]; ar[j] = attn_r[tc * 8 + j]; }
#pragma unroll
    for (int i = 0; i < 2; ++i) {
        int node = node0 + tr + 32 * i;
        float pl = 0.f, pr = 0.f;
#pragma unroll
        for (int j = 0; j < 8; ++j) { pl += acc[i][j] * al[j]; pr += acc[i][j] * ar[j]; }
        pl += __shfl_xor(pl, 1); pl += __shfl_xor(pl, 2); pl += __shfl_xor(pl, 4);
        pr += __shfl_xor(pr, 1); pr += __shfl_xor(pr, 2); pr += __shfl_xor(pr, 4);
        if (node < n) {
            uint4 pk;
            pk.x = packbf2(acc[i][0], acc[i][1]);
            pk.y = packbf2(acc[i][2], acc[i][3]);
            pk.z = packbf2(acc[i][4], acc[i][5]);
            pk.w = packbf2(acc[i][6], acc[i][7]);
            *(uint4*)(feat + (size_t)node * 64 + tc * 8) = pk;
            if (tc == 0) { el[node] = pl; er[node] = pr; }
        }
    }
}

// ---------------- Attention weights, layer 1 (H=4) ----------------

__global__ __launch_bounds__(256) void k_attn_w1(const int* __restrict__ row_start,
                                                 const int* __restrict__ csr_src,
                                                 const float* __restrict__ el,
                                                 const float* __restrict__ er,
                                                 float* __restrict__ alpha,
                                                 float* __restrict__ rden, int n) {
    int wid = (blockIdx.x * blockDim.x + threadIdx.x) >> 6;
    int lane = threadIdx.x & 63;
    if (wid >= n) return;
    int start = row_start[wid], end = row_start[wid + 1];
    float4 er4 = *(const float4*)(er + wid * 4);
    float m0 = -INFINITY, m1 = -INFINITY, m2 = -INFINITY, m3 = -INFINITY;
    for (int slot = start + lane; slot < end; slot += 64) {
        int s = csr_src[slot];
        float4 e4 = *(const float4*)(el + s * 4);
        float e0 = e4.x + er4.x, e1 = e4.y + er4.y, e2 = e4.z + er4.z, e3 = e4.w + er4.w;
        e0 = (e0 > 0.f) ? e0 : 0.2f * e0;
        e1 = (e1 > 0.f) ? e1 : 0.2f * e1;
        e2 = (e2 > 0.f) ? e2 : 0.2f * e2;
        e3 = (e3 > 0.f) ? e3 : 0.2f * e3;
        m0 = fmaxf(m0, e0); m1 = fmaxf(m1, e1); m2 = fmaxf(m2, e2); m3 = fmaxf(m3, e3);
    }
#pragma unroll
    for (int off = 1; off < 64; off <<= 1) {
        m0 = fmaxf(m0, __shfl_xor(m0, off));
        m1 = fmaxf(m1, __shfl_xor(m1, off));
        m2 = fmaxf(m2, __shfl_xor(m2, off));
        m3 = fmaxf(m3, __shfl_xor(m3, off));
    }
    float d0 = 0.f, d1 = 0.f, d2 = 0.f, d3 = 0.f;
    for (int slot = start + lane; slot < end; slot += 64) {
        int s = csr_src[slot];
        float4 e4 = *(const float4*)(el + s * 4);
        float e0 = e4.x + er4.x, e1 = e4.y + er4.y, e2 = e4.z + er4.z, e3 = e4.w + er4.w;
        e0 = (e0 > 0.f) ? e0 : 0.2f * e0;
        e1 = (e1 > 0.f) ? e1 : 0.2f * e1;
        e2 = (e2 > 0.f) ? e2 : 0.2f * e2;
        e3 = (e3 > 0.f) ? e3 : 0.2f * e3;
        float w0 = __expf(e0 - m0), w1 = __expf(e1 - m1);
        float w2 = __expf(e2 - m2), w3 = __expf(e3 - m3);
        d0 += w0; d1 += w1; d2 += w2; d3 += w3;
        *(float4*)(alpha + (size_t)slot * 4) = make_float4(w0, w1, w2, w3);
    }
#pragma unroll
    for (int off = 1; off < 64; off <<= 1) {
        d0 += __shfl_xor(d0, off);
        d1 += __shfl_xor(d1, off);
        d2 += __shfl_xor(d2, off);
        d3 += __shfl_xor(d3, off);
    }
    if (lane == 0) {
        float4 rd;
        rd.x = (d0 > 0.f) ? 1.f / d0 : 0.f;
        rd.y = (d1 > 0.f) ? 1.f / d1 : 0.f;
        rd.z = (d2 > 0.f) ? 1.f / d2 : 0.f;
        rd.w = (d3 > 0.f) ? 1.f / d3 : 0.f;
        *(float4*)(rden + wid * 4) = rd;
    }
}

// ---------------- Attention weights, layer 2 (H=1) ----------------

__global__ __launch_bounds__(256) void k_attn_w2(const int* __restrict__ row_start,
                                                 const int* __restrict__ csr_src,
                                                 const float* __restrict__ el,
                                                 const float* __restrict__ er,
                                                 float* __restrict__ alpha,
                                                 float* __restrict__ rden, int n) {
    int wid = (blockIdx.x * blockDim.x + threadIdx.x) >> 6;
    int lane = threadIdx.x & 63;
    if (wid >= n) return;
    int start = row_start[wid], end = row_start[wid + 1];
    float erv = er[wid];
    float m = -INFINITY;
    for (int slot = start + lane; slot < end; slot += 64) {
        int s = csr_src[slot];
        float e = el[s] + erv;
        e = (e > 0.f) ? e : 0.2f * e;
        m = fmaxf(m, e);
    }
#pragma unroll
    for (int off = 1; off < 64; off <<= 1) m = fmaxf(m, __shfl_xor(m, off));
    float d = 0.f;
    for (int slot = start + lane; slot < end; slot += 64) {
        int s = csr_src[slot];
        float e = el[s] + erv;
        e = (e > 0.f) ? e : 0.2f * e;
        float w = __expf(e - m);
        d += w;
        alpha[slot] = w;
    }
#pragma unroll
    for (int off = 1; off < 64; off <<= 1) d += __shfl_xor(d, off);
    if (lane == 0) rden[wid] = (d > 0.f) ? 1.f / d : 0.f;
}

// ---------------- Gather-accumulate, layer 1 (bf16 feat) ----------------

__global__ __launch_bounds__(256) void k_gather1(const int* __restrict__ row_start,
                                                 const int* __restrict__ csr_src,
                                                 const unsigned short* __restrict__ feat,
                                                 const float* __restrict__ alpha,
                                                 const float* __restrict__ rden,
                                                 const float* __restrict__ bias,
                                                 float* __restrict__ xout, int n) {
    int wid = (blockIdx.x * blockDim.x + threadIdx.x) >> 6;
    int lane = threadIdx.x & 63;
    if (wid >= n) return;
    int g = lane >> 4;    // edge subgroup 0..3
    int dl = lane & 15;   // dims 8*dl .. 8*dl+7
    int h = dl >> 2;      // head
    int start = row_start[wid], end = row_start[wid + 1];
    float A[8] = {};
    int slot = start + g;
    for (; slot + 12 < end; slot += 16) {
        int s0 = csr_src[slot];
        int s1 = csr_src[slot + 4];
        int s2 = csr_src[slot + 8];
        int s3 = csr_src[slot + 12];
        float w0 = alpha[(size_t)slot * 4 + h];
        float w1 = alpha[(size_t)(slot + 4) * 4 + h];
        float w2 = alpha[(size_t)(slot + 8) * 4 + h];
        float w3 = alpha[(size_t)(slot + 12) * 4 + h];
        uint4 f0 = *(const uint4*)(feat + (size_t)s0 * 128 + 8 * dl);
        uint4 f1 = *(const uint4*)(feat + (size_t)s1 * 128 + 8 * dl);
        uint4 f2 = *(const uint4*)(feat + (size_t)s2 * 128 + 8 * dl);
        uint4 f3 = *(const uint4*)(feat + (size_t)s3 * 128 + 8 * dl);
        bf2_fma(f0.x, w0, A[0], A[1]); bf2_fma(f0.y, w0, A[2], A[3]);
        bf2_fma(f0.z, w0, A[4], A[5]); bf2_fma(f0.w, w0, A[6], A[7]);
        bf2_fma(f1.x, w1, A[0], A[1]); bf2_fma(f1.y, w1, A[2], A[3]);
        bf2_fma(f1.z, w1, A[4], A[5]); bf2_fma(f1.w, w1, A[6], A[7]);
        bf2_fma(f2.x, w2, A[0], A[1]); bf2_fma(f2.y, w2, A[2], A[3]);
        bf2_fma(f2.z, w2, A[4], A[5]); bf2_fma(f2.w, w2, A[6], A[7]);
        bf2_fma(f3.x, w3, A[0], A[1]); bf2_fma(f3.y, w3, A[2], A[3]);
        bf2_fma(f3.z, w3, A[4], A[5]); bf2_fma(f3.w, w3, A[6], A[7]);
    }
    for (; slot < end; slot += 4) {
        int s = csr_src[slot];
        float w = alpha[(size_t)slot * 4 + h];
        uint4 f = *(const uint4*)(feat + (size_t)s * 128 + 8 * dl);
        bf2_fma(f.x, w, A[0], A[1]); bf2_fma(f.y, w, A[2], A[3]);
        bf2_fma(f.z, w, A[4], A[5]); bf2_fma(f.w, w, A[6], A[7]);
    }
#pragma unroll
    for (int off = 16; off < 64; off <<= 1) {
#pragma unroll
        for (int j = 0; j < 8; ++j) A[j] += __shfl_xor(A[j], off);
    }
    if (g == 0) {
        float rd = rden[wid * 4 + h];
        const float* bp = bias + 8 * dl;
        float4 b0 = *(const float4*)bp;
        float4 b1 = *(const float4*)(bp + 4);
        float o[8];
        o[0] = A[0] * rd + b0.x; o[1] = A[1] * rd + b0.y;
        o[2] = A[2] * rd + b0.z; o[3] = A[3] * rd + b0.w;
        o[4] = A[4] * rd + b1.x; o[5] = A[5] * rd + b1.y;
        o[6] = A[6] * rd + b1.z; o[7] = A[7] * rd + b1.w;
#pragma unroll
        for (int j = 0; j < 8; ++j) o[j] = (o[j] > 0.f) ? o[j] : (__expf(o[j]) - 1.f);
        float* xp = xout + (size_t)wid * 128 + 8 * dl;
        *(float4*)xp = make_float4(o[0], o[1], o[2], o[3]);
        *(float4*)(xp + 4) = make_float4(o[4], o[5], o[6], o[7]);
    }
}

// ---------------- Gather-accumulate, layer 2 (bf16 feat, final output fp32) ----------------

__global__ __launch_bounds__(256) void k_gather2(const int* __restrict__ row_start,
                                                 const int* __restrict__ csr_src,
                                                 const unsigned short* __restrict__ feat,
                                                 const float* __restrict__ alpha,
                                                 const float* __restrict__ rden,
                                                 const float* __restrict__ bias,
                                                 float* __restrict__ out, int n) {
    int wid = (blockIdx.x * blockDim.x + threadIdx.x) >> 6;
    int lane = threadIdx.x & 63;
    if (wid >= n) return;
    int g = lane >> 3;    // edge subgroup 0..7
    int dl = lane & 7;    // dims 8*dl .. 8*dl+7
    int start = row_start[wid], end = row_start[wid + 1];
    float A[8] = {};
    int slot = start + g;
    for (; slot + 8 < end; slot += 16) {
        int s0 = csr_src[slot];
        int s1 = csr_src[slot + 8];
        float w0 = alpha[slot];
        float w1 = alpha[slot + 8];
        uint4 f0 = *(const uint4*)(feat + (size_t)s0 * 64 + 8 * dl);
        uint4 f1 = *(const uint4*)(feat + (size_t)s1 * 64 + 8 * dl);
        bf2_fma(f0.x, w0, A[0], A[1]); bf2_fma(f0.y, w0, A[2], A[3]);
        bf2_fma(f0.z, w0, A[4], A[5]); bf2_fma(f0.w, w0, A[6], A[7]);
        bf2_fma(f1.x, w1, A[0], A[1]); bf2_fma(f1.y, w1, A[2], A[3]);
        bf2_fma(f1.z, w1, A[4], A[5]); bf2_fma(f1.w, w1, A[6], A[7]);
    }
    if (slot < end) {
        int s = csr_src[slot];
        float w = alpha[slot];
        uint4 f = *(const uint4*)(feat + (size_t)s * 64 + 8 * dl);
        bf2_fma(f.x, w, A[0], A[1]); bf2_fma(f.y, w, A[2], A[3]);
        bf2_fma(f.z, w, A[4], A[5]); bf2_fma(f.w, w, A[6], A[7]);
    }
#pragma unroll
    for (int off = 8; off < 64; off <<= 1) {
#pragma unroll
        for (int j = 0; j < 8; ++j) A[j] += __shfl_xor(A[j], off);
    }
    if (g == 0) {
        float rd = rden[wid];
        const float* bp = bias + 8 * dl;
        float4 b0 = *(const float4*)bp;
        float4 b1 = *(const float4*)(bp + 4);
        float4 o0, o1;
        o0.x = A[0] * rd + b0.x; o0.y = A[1] * rd + b0.y;
        o0.z = A[2] * rd + b0.z; o0.w = A[3] * rd + b0.w;
        o1.x = A[4] * rd + b1.x; o1.y = A[5] * rd + b1.y;
        o1.z = A[6] * rd + b1.z; o1.w = A[7] * rd + b1.w;
        float* op = out + (size_t)wid * 64 + 8 * dl;
        *(float4*)op = o0;
        *(float4*)(op + 4) = o1;
    }
}

// ---------------- launch ----------------

extern "C" void kernel_launch(void* const* d_in, const int* in_sizes, int n_in,
                              void* d_out, int out_size, void* d_ws, size_t ws_size,
                              hipStream_t stream) {
    const float* features = (const float*)d_in[0];
    const int* src = (const int*)d_in[1];
    const int* dst = (const int*)d_in[2];
    const float* fc1_w = (const float*)d_in[3];
    const float* attn_l1 = (const float*)d_in[4];
    const float* attn_r1 = (const float*)d_in[5];
    const float* bias1 = (const float*)d_in[6];
    const float* fc2_w = (const float*)d_in[7];
    const float* attn_l2 = (const float*)d_in[8];
    const float* attn_r2 = (const float*)d_in[9];
    const float* bias2 = (const float*)d_in[10];
    const int N = in_sizes[0] / 128;
    const int E = in_sizes[1];

    char* ws = (char*)d_ws;
    size_t off = 0;
    auto alloc = [&](size_t bytes) {
        void* p = ws + off;
        off = (off + bytes + 255) & ~(size_t)255;
        return p;
    };
    // persistent
    int* cnt = (int*)alloc((size_t)N * 4);
    int* fill = (int*)alloc((size_t)N * 4);
    int* row_start = (int*)alloc((size_t)(N + 1) * 4);
    int* partials = (int*)alloc(1024 * 4);
    int* csr_src = (int*)alloc((size_t)E * 4);
    float* x2 = (float*)alloc((size_t)N * 128 * 4);
    // layer-1 region (reused by layer 2 after k_gather1 completes)
    size_t l1_off = off;
    unsigned short* feat1 = (unsigned short*)alloc((size_t)N * 128 * 2);  // bf16
    float* el1 = (float*)alloc((size_t)N * 4 * 4);
    float* er1 = (float*)alloc((size_t)N * 4 * 4);
    float* alpha1 = (float*)alloc((size_t)E * 4 * 4);
    float* rden1 = (float*)alloc((size_t)N * 4 * 4);
    // layer-2 aliases into layer-1 region (feat1 dead after k_gather1)
    off = l1_off;
    unsigned short* feat2 = (unsigned short*)alloc((size_t)N * 64 * 2);   // bf16
    float* el2 = (float*)alloc((size_t)N * 4);
    float* er2 = (float*)alloc((size_t)N * 4);
    float* alpha2 = (float*)alloc((size_t)E * 4);
    float* rden2 = (float*)alloc((size_t)N * 4);

    hipMemsetAsync(cnt, 0, (size_t)N * 4, stream);

    // gemm1 with embedded fire-and-forget count (grid covers both jobs)
    int ngemm = (N + 63) / 64;
    int ncount = (E + 1023) / 1024;
    int nblk = (ngemm > ncount) ? ngemm : ncount;
    k_gemm1_count<<<nblk, 256, 0, stream>>>(dst, cnt, E,
                                            features, fc1_w, attn_l1, attn_r1,
                                            feat1, el1, er1, N);
    int nb = (N + 1023) / 1024;
    k_scan_local<<<nb, 256, 0, stream>>>(cnt, row_start, partials, N);
    k_scan_partials<<<1, 256, 0, stream>>>(partials, nb);
    k_scan_add<<<(N + 255) / 256, 256, 0, stream>>>(row_start, fill, partials, N, E);
    k_scatter<<<(E + 1023) / 1024, 256, 0, stream>>>(src, dst, fill, csr_src, E);

    int nwave = (N + 3) / 4;
    k_attn_w1<<<nwave, 256, 0, stream>>>(row_start, csr_src, el1, er1, alpha1, rden1, N);
    k_gather1<<<nwave, 256, 0, stream>>>(row_start, csr_src, feat1, alpha1, rden1, bias1, x2, N);
    k_gemm2<<<(N + 63) / 64, 256, 0, stream>>>(x2, fc2_w, attn_l2, attn_r2, feat2, el2, er2, N);
    k_attn_w2<<<nwave, 256, 0, stream>>>(row_start, csr_src, el2, er2, alpha2, rden2, N);
    k_gather2<<<nwave, 256, 0, stream>>>(row_start, csr_src, feat2, alpha2, rden2, bias2, (float*)d_out, N);
}